// Round 1
// baseline (1467.369 us; speedup 1.0000x reference)
//
#include <hip/hip_runtime.h>
#include <math.h>

#define N_NODES 25000
#define E_EDGES 300000
#define K_NB 16

// ---------------------------------------------------------------------------
// gemm64: out[M,64] = X[M,64] @ W[64,64] (+ bias[64])
// block = 256 threads, 16 rows/block; thread computes 1 row x 4 cols
// ---------------------------------------------------------------------------
__global__ __launch_bounds__(256) void gemm64_kernel(
    const float* __restrict__ X, const float* __restrict__ W,
    const float* __restrict__ bias, float* __restrict__ out, int M)
{
    __shared__ float xs[16 * 65];   // +1 pad: banks (rl*65+k)%32 distinct
    const int t = threadIdx.x;
    const int rowBase = blockIdx.x * 16;
    #pragma unroll
    for (int j = 0; j < 4; ++j) {
        int idx = t + j * 256;          // 0..1023
        int r = idx >> 6, c = idx & 63;
        int gr = rowBase + r;
        xs[r * 65 + c] = (gr < M) ? X[(size_t)gr * 64 + c] : 0.0f;
    }
    __syncthreads();
    const int a0 = (t & 15) * 4;
    const int rl = t >> 4;              // 0..15
    const int gr = rowBase + rl;
    float acc0 = 0.f, acc1 = 0.f, acc2 = 0.f, acc3 = 0.f;
    #pragma unroll 8
    for (int k = 0; k < 64; ++k) {
        float xv = xs[rl * 65 + k];
        const float4 w = *(const float4*)(W + k * 64 + a0);
        acc0 = fmaf(xv, w.x, acc0);
        acc1 = fmaf(xv, w.y, acc1);
        acc2 = fmaf(xv, w.z, acc2);
        acc3 = fmaf(xv, w.w, acc3);
    }
    if (gr < M) {
        if (bias) {
            acc0 += bias[a0 + 0]; acc1 += bias[a0 + 1];
            acc2 += bias[a0 + 2]; acc3 += bias[a0 + 3];
        }
        float4 o = { acc0, acc1, acc2, acc3 };
        *(float4*)(out + (size_t)gr * 64 + a0) = o;
    }
}

// ---------------------------------------------------------------------------
// atten1: per node n (one wave, lane = feature/atten dim):
//   av[k,a] = pre[n,a] + gw[vw-1,a] + gj[vj-1,a]   (index 0 -> zero row)
//   x[k]    = sum_a relu(av)*v[a];  a = softmax_k(x);  out[n] = sum_k a*ej[vj-1]
// ---------------------------------------------------------------------------
__global__ __launch_bounds__(256) void atten1_kernel(
    const float* __restrict__ pre,   // [N,64] = ev@W1[:F] + b
    const float* __restrict__ gw,    // [E,64] = ew@W1[F:]
    const float* __restrict__ gj,    // [N,64] = ej@W2
    const float* __restrict__ ej,    // [N,64]
    const float* __restrict__ v,     // [64]
    const int* __restrict__ Vj, const int* __restrict__ Vw,
    float* __restrict__ out)         // [N,64]
{
    const int lane = threadIdx.x & 63;
    const int n = blockIdx.x * 4 + (threadIdx.x >> 6);
    if (n >= N_NODES) return;
    const float prev = pre[(size_t)n * 64 + lane];
    const float vv = v[lane];
    float gwv[K_NB], gjv[K_NB];
    int vj[K_NB];
    #pragma unroll
    for (int k = 0; k < K_NB; ++k) {
        int w = Vw[n * K_NB + k];
        vj[k] = Vj[n * K_NB + k];
        gwv[k] = (w > 0) ? gw[(size_t)(w - 1) * 64 + lane] : 0.0f;
        gjv[k] = (vj[k] > 0) ? gj[(size_t)(vj[k] - 1) * 64 + lane] : 0.0f;
    }
    float x[K_NB];
    #pragma unroll
    for (int k = 0; k < K_NB; ++k) {
        float av = fmaxf(prev + gwv[k] + gjv[k], 0.0f) * vv;
        #pragma unroll
        for (int off = 32; off > 0; off >>= 1) av += __shfl_xor(av, off, 64);
        x[k] = av;
    }
    float m = x[0];
    #pragma unroll
    for (int k = 1; k < K_NB; ++k) m = fmaxf(m, x[k]);
    float s = 0.f;
    #pragma unroll
    for (int k = 0; k < K_NB; ++k) { x[k] = __expf(x[k] - m); s += x[k]; }
    const float inv = 1.0f / s;
    float acc = 0.f;
    #pragma unroll
    for (int k = 0; k < K_NB; ++k) {
        float e = (vj[k] > 0) ? ej[(size_t)(vj[k] - 1) * 64 + lane] : 0.0f;
        acc = fmaf(x[k] * inv, e, acc);
    }
    out[(size_t)n * 64 + lane] = acc;
}

// ---------------------------------------------------------------------------
// fused tail: atten2 + bit/vec convs + final [16,560]@Wf[560,64] per block
// block = 256 threads = 4 waves, 16 nodes/block, blockIdx.y = type (u,i,t)
// ---------------------------------------------------------------------------
__global__ __launch_bounds__(256) void fused_kernel(
    const float* __restrict__ xu0, const float* __restrict__ xu1, const float* __restrict__ xu2,
    const float* __restrict__ xi0, const float* __restrict__ xi1, const float* __restrict__ xi2,
    const float* __restrict__ xt0, const float* __restrict__ xt1, const float* __restrict__ xt2,
    const float* __restrict__ U, const float* __restrict__ q, const float* __restrict__ p,
    const float* __restrict__ Wbit, const float* __restrict__ Wv1,
    const float* __restrict__ Wv2, const float* __restrict__ Wv3,
    const float* __restrict__ Wf, const float* __restrict__ bfv,
    float* __restrict__ out)
{
    // c stride 564: 564%32=20 -> 16 node rows hit >=8 distinct banks (2-way ok),
    // and 564%4==0 keeps float4 alignment for phase C.
    __shared__ __align__(16) float c_lds[16 * 564];
    __shared__ float eN_lds[16 * 193];  // 193%32=1 -> node rows conflict-free
    const int t = threadIdx.x;
    const int lane = t & 63;
    const int wv = t >> 6;
    const int type = blockIdx.y;
    const int nodeBase = blockIdx.x * 16;
    const float* x0 = (type == 0) ? xu0 : (type == 1) ? xi0 : xt0;
    const float* x1 = (type == 0) ? xu1 : (type == 1) ? xi1 : xt1;
    const float* x2 = (type == 0) ? xu2 : (type == 1) ? xi2 : xt2;
    const float qv = q[lane], pv = p[lane];
    float wb[8][3];
    #pragma unroll
    for (int c = 0; c < 8; ++c)
        #pragma unroll
        for (int s = 0; s < 3; ++s) wb[c][s] = Wbit[c * 3 + s];

    // ---- Phase A: atten2 + bit conv (each wave: 4 nodes sequentially) ----
    for (int i = 0; i < 4; ++i) {
        const int nl = wv * 4 + i;
        const int n = nodeBase + nl;
        float u0 = 0.f, u1 = 0.f, u2 = 0.f;
        if (n < N_NODES) {
            u0 = x0[(size_t)n * 64 + lane];
            u1 = x1[(size_t)n * 64 + lane];
            u2 = x2[(size_t)n * 64 + lane];
        }
        float av0 = qv, av1 = qv, av2 = qv;
        #pragma unroll 8
        for (int f = 0; f < 64; ++f) {
            float Uc = U[f * 64 + lane];
            av0 = fmaf(__shfl(u0, f, 64), Uc, av0);
            av1 = fmaf(__shfl(u1, f, 64), Uc, av1);
            av2 = fmaf(__shfl(u2, f, 64), Uc, av2);
        }
        float xs0 = fmaxf(av0, 0.f) * pv;
        float xs1 = fmaxf(av1, 0.f) * pv;
        float xs2 = fmaxf(av2, 0.f) * pv;
        #pragma unroll
        for (int off = 32; off > 0; off >>= 1) {
            xs0 += __shfl_xor(xs0, off, 64);
            xs1 += __shfl_xor(xs1, off, 64);
            xs2 += __shfl_xor(xs2, off, 64);
        }
        float m = fmaxf(xs0, fmaxf(xs1, xs2));
        float e0 = __expf(xs0 - m), e1 = __expf(xs1 - m), e2 = __expf(xs2 - m);
        float inv = 1.0f / (e0 + e1 + e2);
        float en0 = e0 * inv * u0, en1 = e1 * inv * u1, en2 = e2 * inv * u2;
        eN_lds[nl * 193 + lane] = en0;
        eN_lds[nl * 193 + 64 + lane] = en1;
        eN_lds[nl * 193 + 128 + lane] = en2;
        #pragma unroll
        for (int c = 0; c < 8; ++c) {
            float bc = fmaxf(wb[c][0] * en0 + wb[c][1] * en1 + wb[c][2] * en2, 0.f);
            c_lds[nl * 564 + c * 64 + lane] = bc;
        }
    }
    __syncthreads();

    // ---- Phase B: vec convs, 768 outputs = 48 per node x 16 nodes ----
    // o = v*16 + node; type boundaries (24,40) are multiples of 4 so each
    // wave's 4 consecutive v-values share the same window length R.
    #pragma unroll
    for (int i = 0; i < 3; ++i) {
        const int o = i * 256 + t;
        const int vv = o >> 4, nl = o & 15;
        const float* wr; int s0, R;
        if (vv < 24)      { wr = Wv1 + (vv / 3) * 64;            s0 = vv % 3;        R = 1; }
        else if (vv < 40) { int u = vv - 24; wr = Wv2 + (u >> 1) * 128; s0 = u & 1;  R = 2; }
        else              { wr = Wv3 + (vv - 40) * 192;          s0 = 0;             R = 3; }
        float acc = 0.f;
        for (int r = 0; r < R; ++r) {
            const float* e = &eN_lds[nl * 193 + (s0 + r) * 64];
            const float* w = wr + r * 64;
            #pragma unroll 8
            for (int f = 0; f < 64; ++f) acc = fmaf(w[f], e[f], acc);
        }
        c_lds[nl * 564 + 512 + vv] = fmaxf(acc, 0.f);
    }
    __syncthreads();

    // ---- Phase C: out[16,64] = relu(c[16,560] @ Wf + bf) ----
    const int o = lane;
    const int g = wv;                       // wave g -> nodes g*4..g*4+3
    const float bfo = bfv[o];
    float acc0 = 0.f, acc1 = 0.f, acc2 = 0.f, acc3 = 0.f;
    for (int idx = 0; idx < 560; idx += 4) {
        float wf0 = Wf[(idx + 0) * 64 + o];
        float wf1 = Wf[(idx + 1) * 64 + o];
        float wf2 = Wf[(idx + 2) * 64 + o];
        float wf3 = Wf[(idx + 3) * 64 + o];
        float4 c0 = *(const float4*)&c_lds[(g * 4 + 0) * 564 + idx];
        float4 c1 = *(const float4*)&c_lds[(g * 4 + 1) * 564 + idx];
        float4 c2 = *(const float4*)&c_lds[(g * 4 + 2) * 564 + idx];
        float4 c3 = *(const float4*)&c_lds[(g * 4 + 3) * 564 + idx];
        acc0 += c0.x * wf0 + c0.y * wf1 + c0.z * wf2 + c0.w * wf3;
        acc1 += c1.x * wf0 + c1.y * wf1 + c1.z * wf2 + c1.w * wf3;
        acc2 += c2.x * wf0 + c2.y * wf1 + c2.z * wf2 + c2.w * wf3;
        acc3 += c3.x * wf0 + c3.y * wf1 + c3.z * wf2 + c3.w * wf3;
    }
    float* outT = out + (size_t)type * N_NODES * 64;
    const float accs[4] = { acc0, acc1, acc2, acc3 };
    #pragma unroll
    for (int nn = 0; nn < 4; ++nn) {
        int n = nodeBase + g * 4 + nn;
        if (n < N_NODES) outT[(size_t)n * 64 + o] = fmaxf(accs[nn] + bfo, 0.f);
    }
}

// ---------------------------------------------------------------------------
extern "C" void kernel_launch(void* const* d_in, const int* in_sizes, int n_in,
                              void* d_out, int out_size, void* d_ws, size_t ws_size,
                              hipStream_t stream)
{
    const float* eu = (const float*)d_in[0];
    const float* ei = (const float*)d_in[1];
    const float* et = (const float*)d_in[2];
    const float* ew = (const float*)d_in[3];
    const int* u_iw_j = (const int*)d_in[4];
    const int* u_iw_w = (const int*)d_in[5];
    const int* u_tw_j = (const int*)d_in[6];
    const int* u_tw_w = (const int*)d_in[7];
    const int* i_uw_j = (const int*)d_in[8];
    const int* i_uw_w = (const int*)d_in[9];
    const int* i_tw_j = (const int*)d_in[10];
    const int* i_tw_w = (const int*)d_in[11];
    const int* t_uw_j = (const int*)d_in[12];
    const int* t_uw_w = (const int*)d_in[13];
    const int* t_iw_j = (const int*)d_in[14];
    const int* t_iw_w = (const int*)d_in[15];
    const float* W1_user = (const float*)d_in[16];
    const float* W2_user = (const float*)d_in[17];
    const float* b_user  = (const float*)d_in[18];
    const float* v_user  = (const float*)d_in[19];
    const float* W1_item = (const float*)d_in[20];
    const float* W2_item = (const float*)d_in[21];
    const float* b_item  = (const float*)d_in[22];
    const float* v_item  = (const float*)d_in[23];
    const float* W1_tag  = (const float*)d_in[24];
    const float* W2_tag  = (const float*)d_in[25];
    const float* b_tag   = (const float*)d_in[26];
    const float* v_tag   = (const float*)d_in[27];
    const float* U    = (const float*)d_in[28];
    const float* q    = (const float*)d_in[29];
    const float* p    = (const float*)d_in[30];
    const float* Wbit = (const float*)d_in[31];
    const float* Wv1  = (const float*)d_in[32];
    const float* Wv2  = (const float*)d_in[33];
    const float* Wv3  = (const float*)d_in[34];
    const float* Wf   = (const float*)d_in[35];
    const float* bfv  = (const float*)d_in[36];
    float* out = (float*)d_out;

    // ---- workspace layout (fp32): peak 43.2M floats = 172.8 MB ----
    const size_t NV = (size_t)N_NODES * 64;
    float* ws  = (float*)d_ws;
    float* gw  = ws;                               // E*64 (reused per W1 group)
    float* pre = gw + (size_t)E_EDGES * 64;        // 6 x N*64
    float* gj  = pre + 6 * NV;                     // 3 x N*64 (order: u,i,t)
    float* ao  = gj + 3 * NV;                      // 6 x N*64 atten1 outputs

    const dim3 blk(256);
    const int gN = (N_NODES + 15) / 16;            // 1563
    const int gE = (E_EDGES + 15) / 16;            // 18750
    const int gA = (N_NODES + 3) / 4;              // 6250

    // pre[c] = ev @ W1[:F] + b  (W1 is [128,64] row-major; rows 64.. = +4096)
    gemm64_kernel<<<gN, blk, 0, stream>>>(eu, W1_item, b_item, pre + 0 * NV, N_NODES);
    gemm64_kernel<<<gN, blk, 0, stream>>>(eu, W1_tag,  b_tag,  pre + 1 * NV, N_NODES);
    gemm64_kernel<<<gN, blk, 0, stream>>>(ei, W1_user, b_user, pre + 2 * NV, N_NODES);
    gemm64_kernel<<<gN, blk, 0, stream>>>(ei, W1_tag,  b_tag,  pre + 3 * NV, N_NODES);
    gemm64_kernel<<<gN, blk, 0, stream>>>(et, W1_user, b_user, pre + 4 * NV, N_NODES);
    gemm64_kernel<<<gN, blk, 0, stream>>>(et, W1_item, b_item, pre + 5 * NV, N_NODES);
    // gj = ej @ W2 per type
    gemm64_kernel<<<gN, blk, 0, stream>>>(eu, W2_user, (const float*)nullptr, gj + 0 * NV, N_NODES);
    gemm64_kernel<<<gN, blk, 0, stream>>>(ei, W2_item, (const float*)nullptr, gj + 1 * NV, N_NODES);
    gemm64_kernel<<<gN, blk, 0, stream>>>(et, W2_tag,  (const float*)nullptr, gj + 2 * NV, N_NODES);

    // --- item group: gw = ew @ W1_item[F:] ---
    gemm64_kernel<<<gE, blk, 0, stream>>>(ew, W1_item + 4096, (const float*)nullptr, gw, E_EDGES);
    atten1_kernel<<<gA, blk, 0, stream>>>(pre + 0 * NV, gw, gj + 1 * NV, ei, v_item, u_iw_j, u_iw_w, ao + 0 * NV); // eu_iN
    atten1_kernel<<<gA, blk, 0, stream>>>(pre + 5 * NV, gw, gj + 1 * NV, ei, v_item, t_iw_j, t_iw_w, ao + 5 * NV); // et_iN
    // --- tag group ---
    gemm64_kernel<<<gE, blk, 0, stream>>>(ew, W1_tag + 4096, (const float*)nullptr, gw, E_EDGES);
    atten1_kernel<<<gA, blk, 0, stream>>>(pre + 1 * NV, gw, gj + 2 * NV, et, v_tag, u_tw_j, u_tw_w, ao + 1 * NV);  // eu_tN
    atten1_kernel<<<gA, blk, 0, stream>>>(pre + 3 * NV, gw, gj + 2 * NV, et, v_tag, i_tw_j, i_tw_w, ao + 3 * NV);  // ei_tN
    // --- user group ---
    gemm64_kernel<<<gE, blk, 0, stream>>>(ew, W1_user + 4096, (const float*)nullptr, gw, E_EDGES);
    atten1_kernel<<<gA, blk, 0, stream>>>(pre + 2 * NV, gw, gj + 0 * NV, eu, v_user, i_uw_j, i_uw_w, ao + 2 * NV); // ei_uN
    atten1_kernel<<<gA, blk, 0, stream>>>(pre + 4 * NV, gw, gj + 0 * NV, eu, v_user, t_uw_j, t_uw_w, ao + 4 * NV); // et_uN

    // --- fused atten2 + convs + final linear, all 3 types ---
    fused_kernel<<<dim3(gN, 3), blk, 0, stream>>>(
        eu, ao + 0 * NV, ao + 1 * NV,          // type u: (eu, eu_iN, eu_tN)
        ao + 2 * NV, ei, ao + 3 * NV,          // type i: (ei_uN, ei, ei_tN)
        ao + 4 * NV, ao + 5 * NV, et,          // type t: (et_uN, et_iN, et)
        U, q, p, Wbit, Wv1, Wv2, Wv3, Wf, bfv, out);
}

// Round 2
// 939.507 us; speedup vs baseline: 1.5619x; 1.5619x over previous
//
#include <hip/hip_runtime.h>
#include <math.h>

#define NN 25000
#define EE 300000
#define NT 1563   // ceil(25000/16)

typedef __attribute__((ext_vector_type(8))) short bf16x8;
typedef __attribute__((ext_vector_type(4))) float f32x4;

__device__ __forceinline__ unsigned short f2bf(float f) {
    union { float f; unsigned u; } a; a.f = f;
    unsigned r = (a.u + 0x7fffu + ((a.u >> 16) & 1u)) >> 16;   // RNE
    return (unsigned short)r;
}
__device__ __forceinline__ unsigned pack2(float lo, float hi) {
    return (unsigned)f2bf(lo) | ((unsigned)f2bf(hi) << 16);
}
__device__ __forceinline__ float bflo(unsigned p) {
    union { unsigned u; float f; } a; a.u = p << 16; return a.f;
}
__device__ __forceinline__ float bfhi(unsigned p) {
    union { unsigned u; float f; } a; a.u = p & 0xffff0000u; return a.f;
}

// ---------------------------------------------------------------------------
// ngemm: 9 fused [N,64]@[64,64] products (grid.y selects), bf16 outputs.
// y 0..5 -> preB[y] = X@W1x[0:64] + b  (bf16 pairs)
// y 6..8 -> JE[y-6] : per pair p: (gj[2p],gj[2p+1],ej[2p],ej[2p+1]) bf16
// ---------------------------------------------------------------------------
__global__ __launch_bounds__(256) void ngemm_kernel(
    const float* __restrict__ eu, const float* __restrict__ ei, const float* __restrict__ et,
    const float* __restrict__ W1u, const float* __restrict__ W1i, const float* __restrict__ W1t,
    const float* __restrict__ W2u, const float* __restrict__ W2i, const float* __restrict__ W2t,
    const float* __restrict__ bu, const float* __restrict__ bi, const float* __restrict__ bt,
    unsigned* __restrict__ preB, uint2* __restrict__ JE)
{
    __shared__ float xs[16 * 65];
    const int t = threadIdx.x;
    const int y = blockIdx.y;
    const float* X; const float* W; const float* bias = nullptr;
    switch (y) {
        case 0: X = eu; W = W1i; bias = bi; break;
        case 1: X = eu; W = W1t; bias = bt; break;
        case 2: X = ei; W = W1u; bias = bu; break;
        case 3: X = ei; W = W1t; bias = bt; break;
        case 4: X = et; W = W1u; bias = bu; break;
        case 5: X = et; W = W1i; bias = bi; break;
        case 6: X = eu; W = W2u; break;
        case 7: X = ei; W = W2i; break;
        default: X = et; W = W2t; break;
    }
    const int rowBase = blockIdx.x * 16;
    #pragma unroll
    for (int jj = 0; jj < 4; ++jj) {
        int idx = t + jj * 256;
        int r = idx >> 6, c = idx & 63;
        int gr = rowBase + r;
        xs[r * 65 + c] = (gr < NN) ? X[(size_t)gr * 64 + c] : 0.0f;
    }
    __syncthreads();
    const int g = t & 15;
    const int a0 = g * 4;
    const int rl = t >> 4;
    const int gr = rowBase + rl;
    float acc0 = 0.f, acc1 = 0.f, acc2 = 0.f, acc3 = 0.f;
    #pragma unroll 8
    for (int k = 0; k < 64; ++k) {
        float xv = xs[rl * 65 + k];
        const float4 w = *(const float4*)(W + k * 64 + a0);
        acc0 = fmaf(xv, w.x, acc0); acc1 = fmaf(xv, w.y, acc1);
        acc2 = fmaf(xv, w.z, acc2); acc3 = fmaf(xv, w.w, acc3);
    }
    if (gr >= NN) return;
    if (y < 6) {
        acc0 += bias[a0]; acc1 += bias[a0 + 1]; acc2 += bias[a0 + 2]; acc3 += bias[a0 + 3];
        uint2 o = { pack2(acc0, acc1), pack2(acc2, acc3) };
        *(uint2*)(preB + ((size_t)y * NN + gr) * 32 + g * 2) = o;
    } else {
        float e0 = xs[rl * 65 + a0], e1 = xs[rl * 65 + a0 + 1];
        float e2 = xs[rl * 65 + a0 + 2], e3 = xs[rl * 65 + a0 + 3];
        uint2* row = JE + ((size_t)(y - 6) * NN + gr) * 32;
        row[2 * g]     = make_uint2(pack2(acc0, acc1), pack2(e0, e1));
        row[2 * g + 1] = make_uint2(pack2(acc2, acc3), pack2(e2, e3));
    }
}

// ---------------------------------------------------------------------------
// egemm: gwB = ew[E,64] @ W[64,64], bf16-pair output. E divisible by 16.
// ---------------------------------------------------------------------------
__global__ __launch_bounds__(256) void egemm_kernel(
    const float* __restrict__ X, const float* __restrict__ W,
    unsigned* __restrict__ gwB)
{
    __shared__ float xs[16 * 65];
    const int t = threadIdx.x;
    const int rowBase = blockIdx.x * 16;
    #pragma unroll
    for (int jj = 0; jj < 4; ++jj) {
        int idx = t + jj * 256;
        int r = idx >> 6, c = idx & 63;
        xs[r * 65 + c] = X[(size_t)(rowBase + r) * 64 + c];
    }
    __syncthreads();
    const int g = t & 15;
    const int a0 = g * 4;
    const int rl = t >> 4;
    float acc0 = 0.f, acc1 = 0.f, acc2 = 0.f, acc3 = 0.f;
    #pragma unroll 8
    for (int k = 0; k < 64; ++k) {
        float xv = xs[rl * 65 + k];
        const float4 w = *(const float4*)(W + k * 64 + a0);
        acc0 = fmaf(xv, w.x, acc0); acc1 = fmaf(xv, w.y, acc1);
        acc2 = fmaf(xv, w.z, acc2); acc3 = fmaf(xv, w.w, acc3);
    }
    uint2 o = { pack2(acc0, acc1), pack2(acc2, acc3) };
    *(uint2*)(gwB + (size_t)(rowBase + rl) * 32 + g * 2) = o;
}

// ---------------------------------------------------------------------------
// atten1 (paired; blockIdx.y selects set). bf16 tables, pair-packed lanes:
// half = lane>>5 handles k parity, pl = lane&31 owns features (2pl, 2pl+1).
// ---------------------------------------------------------------------------
__global__ __launch_bounds__(256) void atten1_kernel(
    const unsigned* __restrict__ preB0, const unsigned* __restrict__ preB1,
    const unsigned* __restrict__ gwB, const uint2* __restrict__ JE,
    const float* __restrict__ v0, const float* __restrict__ v1,
    const int* __restrict__ Vj0, const int* __restrict__ Vw0,
    const int* __restrict__ Vj1, const int* __restrict__ Vw1,
    float* __restrict__ out0, float* __restrict__ out1)
{
    const int lane = threadIdx.x & 63;
    const int n = blockIdx.x * 4 + (threadIdx.x >> 6);
    const int sel = blockIdx.y;
    const unsigned* preB = sel ? preB1 : preB0;
    const float* v = sel ? v1 : v0;
    const int* Vj = sel ? Vj1 : Vj0;
    const int* Vw = sel ? Vw1 : Vw0;
    float* out = sel ? out1 : out0;
    const int half = lane >> 5, pl = lane & 31;

    unsigned prep = preB[(size_t)n * 32 + pl];
    const float p0 = bflo(prep), p1 = bfhi(prep);
    const float2 vp = ((const float2*)v)[pl];

    float xk[8]; unsigned ejp[8];
    #pragma unroll
    for (int i = 0; i < 8; ++i) {
        int k = 2 * i + half;
        int w = Vw[n * 16 + k];
        int j = Vj[n * 16 + k];
        unsigned gp = (w > 0) ? gwB[(size_t)(w - 1) * 32 + pl] : 0u;
        uint2 je = (j > 0) ? JE[(size_t)(j - 1) * 32 + pl] : make_uint2(0u, 0u);
        ejp[i] = je.y;
        float x = fmaxf(p0 + bflo(gp) + bflo(je.x), 0.f) * vp.x
                + fmaxf(p1 + bfhi(gp) + bfhi(je.x), 0.f) * vp.y;
        x += __shfl_xor(x, 1, 64);  x += __shfl_xor(x, 2, 64);
        x += __shfl_xor(x, 4, 64);  x += __shfl_xor(x, 8, 64);
        x += __shfl_xor(x, 16, 64);
        xk[i] = x;
    }
    float m = xk[0];
    #pragma unroll
    for (int i = 1; i < 8; ++i) m = fmaxf(m, xk[i]);
    m = fmaxf(m, __shfl_xor(m, 32, 64));
    float s = 0.f;
    #pragma unroll
    for (int i = 0; i < 8; ++i) { xk[i] = __expf(xk[i] - m); s += xk[i]; }
    s += __shfl_xor(s, 32, 64);
    const float inv = 1.f / s;
    float a0 = 0.f, a1 = 0.f;
    #pragma unroll
    for (int i = 0; i < 8; ++i) {
        float wgt = xk[i] * inv;
        a0 = fmaf(wgt, bflo(ejp[i]), a0);
        a1 = fmaf(wgt, bfhi(ejp[i]), a1);
    }
    a0 += __shfl_xor(a0, 32, 64);
    a1 += __shfl_xor(a1, 32, 64);
    if (half == 0) ((float2*)out)[(size_t)n * 32 + pl] = make_float2(a0, a1);
}

// ---------------------------------------------------------------------------
// tail: atten2 + convs + final linear, all MFMA (16x16x32 bf16).
// Per 16-node tile: uit[48,64]@U (phase A) -> softmax (prestep) ->
// en + bit conv (A2) -> G = eN[48,64]@WconvT[64,48] (B) -> vec assembly (B2)
// -> out[16,64] = relu(c[16,576]@Wf) (C, Wf strips register-resident).
// grid-stride over tiles so Wf fragments load once per block.
// ---------------------------------------------------------------------------
__global__ __launch_bounds__(256, 3) void tail_kernel(
    const float* __restrict__ xu0, const float* __restrict__ xu1, const float* __restrict__ xu2,
    const float* __restrict__ xi0, const float* __restrict__ xi1, const float* __restrict__ xi2,
    const float* __restrict__ xt0, const float* __restrict__ xt1, const float* __restrict__ xt2,
    const float* __restrict__ U, const float* __restrict__ q, const float* __restrict__ p,
    const float* __restrict__ Wbit, const float* __restrict__ Wv1,
    const float* __restrict__ Wv2, const float* __restrict__ Wv3,
    const float* __restrict__ Wf, const float* __restrict__ bfv,
    float* __restrict__ out)
{
    // stride 72 u16 (144 B = 9*16B): b128 A-frag reads 16B-aligned, 9 odd -> conflict-free
    __shared__ __align__(16) unsigned short uitA[48 * 72];
    __shared__ __align__(16) unsigned short eNA[48 * 72];
    __shared__ __align__(16) unsigned short wcf[6 * 64 * 8];  // Wconv B-frags, frag-layout
    __shared__ __align__(16) unsigned short c_sh[16 * 584];   // 584*2B = 73*16B
    __shared__ float G_sh[48 * 52];
    __shared__ float xpart[4 * 48];
    __shared__ float bcoef[16 * 4];

    const int t = threadIdx.x;
    const int lane = t & 63;
    const int wv = t >> 6;
    const int l15 = lane & 15;
    const int quad = lane >> 4;
    const int type = blockIdx.y;
    const float* x0 = (type == 0) ? xu0 : (type == 1) ? xi0 : xt0;
    const float* x1 = (type == 0) ? xu1 : (type == 1) ? xi1 : xt1;
    const float* x2 = (type == 0) ? xu2 : (type == 1) ? xi2 : xt2;
    const int cw = wv * 16 + l15;           // this wave's output/U column
    const float qv = q[cw], pv = p[cw], bfb = bfv[cw];

    float wb[8][3];
    #pragma unroll
    for (int c = 0; c < 8; ++c)
        #pragma unroll
        for (int s = 0; s < 3; ++s) wb[c][s] = Wbit[c * 3 + s];

    // U B-frags (this wave's 16-col strip), k = ks*32 + quad*8 + j
    bf16x8 ufrag[2];
    #pragma unroll
    for (int ks = 0; ks < 2; ++ks)
        #pragma unroll
        for (int j = 0; j < 8; ++j) {
            int f = ks * 32 + quad * 8 + j;
            ufrag[ks][j] = (short)f2bf(U[f * 64 + cw]);
        }
    // Wf B-frags: 18 k-steps cover K=576 (560 real + zero pad)
    bf16x8 wff[18];
    #pragma unroll
    for (int ks = 0; ks < 18; ++ks)
        #pragma unroll
        for (int j = 0; j < 8; ++j) {
            int k = ks * 32 + quad * 8 + j;
            float w = (k < 560) ? Wf[(size_t)k * 64 + cw] : 0.f;
            wff[ks][j] = (short)f2bf(w);
        }
    // Wconv B-frags into LDS (shared by all waves; built once)
    for (int slot = t; slot < 384; slot += 256) {
        int fi = slot >> 6, l = slot & 63;
        int nt_ = fi >> 1, ks = fi & 1;
        int r = nt_ * 16 + (l & 15);
        unsigned short vals[8];
        #pragma unroll
        for (int j = 0; j < 8; ++j) {
            int f = ks * 32 + (l >> 4) * 8 + j;
            float wv_;
            if (r < 8)       wv_ = Wv1[r * 64 + f];
            else if (r < 24) { int u = r - 8;  wv_ = Wv2[(u >> 1) * 128 + (u & 1) * 64 + f]; }
            else             { int u = r - 24; wv_ = Wv3[(u / 3) * 192 + (u % 3) * 64 + f]; }
            vals[j] = f2bf(wv_);
        }
        uint4 pk = { (unsigned)vals[0] | ((unsigned)vals[1] << 16),
                     (unsigned)vals[2] | ((unsigned)vals[3] << 16),
                     (unsigned)vals[4] | ((unsigned)vals[5] << 16),
                     (unsigned)vals[6] | ((unsigned)vals[7] << 16) };
        *(uint4*)&wcf[slot * 8] = pk;
    }

    for (int tile = blockIdx.x; tile < NT; tile += gridDim.x) {
        const int nodeBase = tile * 16;
        __syncthreads();
        // ---- stage uit (48 rows = 16 nodes x 3 sources) as bf16 ----
        #pragma unroll
        for (int i = 0; i < 3; ++i) {
            int idx = t + i * 256;                 // 0..767
            int row = idx >> 4, cg = idx & 15;
            int nl = row / 3, s = row - nl * 3;
            const float* src = (s == 0) ? x0 : (s == 1) ? x1 : x2;
            int n = nodeBase + nl;
            float4 v4 = (n < NN) ? *(const float4*)(src + (size_t)n * 64 + cg * 4)
                                 : make_float4(0.f, 0.f, 0.f, 0.f);
            uint2 pk = { pack2(v4.x, v4.y), pack2(v4.z, v4.w) };
            *(uint2*)&uitA[row * 72 + cg * 4] = pk;
        }
        __syncthreads();
        // ---- phase A: av = uit @ U; per-wave column-strip partial x ----
        {
            f32x4 av[3];
            #pragma unroll
            for (int mt = 0; mt < 3; ++mt) { av[mt].x = 0; av[mt].y = 0; av[mt].z = 0; av[mt].w = 0; }
            #pragma unroll
            for (int mt = 0; mt < 3; ++mt)
                #pragma unroll
                for (int ks = 0; ks < 2; ++ks) {
                    bf16x8 a = *(const bf16x8*)&uitA[(mt * 16 + l15) * 72 + ks * 32 + quad * 8];
                    av[mt] = __builtin_amdgcn_mfma_f32_16x16x32_bf16(a, ufrag[ks], av[mt], 0, 0, 0);
                }
            #pragma unroll
            for (int mt = 0; mt < 3; ++mt)
                #pragma unroll
                for (int r = 0; r < 4; ++r) {
                    float val = fmaxf(av[mt][r] + qv, 0.f) * pv;
                    val += __shfl_xor(val, 1, 64); val += __shfl_xor(val, 2, 64);
                    val += __shfl_xor(val, 4, 64); val += __shfl_xor(val, 8, 64);
                    if (l15 == 0) xpart[wv * 48 + mt * 16 + quad * 4 + r] = val;
                }
        }
        __syncthreads();
        // ---- prestep: per-node softmax over s ----
        if (t < 16) {
            float xv[3];
            #pragma unroll
            for (int s = 0; s < 3; ++s)
                xv[s] = xpart[t * 3 + s] + xpart[48 + t * 3 + s]
                      + xpart[96 + t * 3 + s] + xpart[144 + t * 3 + s];
            float mm = fmaxf(xv[0], fmaxf(xv[1], xv[2]));
            float e0 = __expf(xv[0] - mm), e1 = __expf(xv[1] - mm), e2 = __expf(xv[2] - mm);
            float inv = 1.f / (e0 + e1 + e2);
            bcoef[t * 4 + 0] = e0 * inv; bcoef[t * 4 + 1] = e1 * inv; bcoef[t * 4 + 2] = e2 * inv;
        }
        __syncthreads();
        // ---- phase A2: en = b*uit (bf16), bit conv -> c_sh[0:512] ----
        #pragma unroll
        for (int i = 0; i < 2; ++i) {
            int task = t + i * 256;                // 0..511
            int nl = task >> 5, fp = task & 31;
            float b0 = bcoef[nl * 4], b1 = bcoef[nl * 4 + 1], b2 = bcoef[nl * 4 + 2];
            unsigned u0 = *(const unsigned*)&uitA[(nl * 3 + 0) * 72 + fp * 2];
            unsigned u1 = *(const unsigned*)&uitA[(nl * 3 + 1) * 72 + fp * 2];
            unsigned u2 = *(const unsigned*)&uitA[(nl * 3 + 2) * 72 + fp * 2];
            float e0l = b0 * bflo(u0), e0h = b0 * bfhi(u0);
            float e1l = b1 * bflo(u1), e1h = b1 * bfhi(u1);
            float e2l = b2 * bflo(u2), e2h = b2 * bfhi(u2);
            *(unsigned*)&eNA[(nl * 3 + 0) * 72 + fp * 2] = pack2(e0l, e0h);
            *(unsigned*)&eNA[(nl * 3 + 1) * 72 + fp * 2] = pack2(e1l, e1h);
            *(unsigned*)&eNA[(nl * 3 + 2) * 72 + fp * 2] = pack2(e2l, e2h);
            #pragma unroll
            for (int c = 0; c < 8; ++c) {
                float lo = fmaxf(wb[c][0] * e0l + wb[c][1] * e1l + wb[c][2] * e2l, 0.f);
                float hi = fmaxf(wb[c][0] * e0h + wb[c][1] * e1h + wb[c][2] * e2h, 0.f);
                *(unsigned*)&c_sh[nl * 584 + c * 64 + fp * 2] = pack2(lo, hi);
            }
        }
        __syncthreads();
        // ---- phase B: G = eN @ WconvT; 9 (m,n) 16x16 tiles round-robin ----
        #pragma unroll
        for (int pi = 0; pi < 3; ++pi) {
            int pr = wv + pi * 4;
            if (pr < 9) {
                int mm = pr / 3, nn_ = pr - mm * 3;
                f32x4 g; g.x = 0; g.y = 0; g.z = 0; g.w = 0;
                #pragma unroll
                for (int ks = 0; ks < 2; ++ks) {
                    bf16x8 a = *(const bf16x8*)&eNA[(mm * 16 + l15) * 72 + ks * 32 + quad * 8];
                    bf16x8 b = *(const bf16x8*)&wcf[((nn_ * 2 + ks) * 64 + lane) * 8];
                    g = __builtin_amdgcn_mfma_f32_16x16x32_bf16(a, b, g, 0, 0, 0);
                }
                #pragma unroll
                for (int r = 0; r < 4; ++r)
                    G_sh[(mm * 16 + quad * 4 + r) * 52 + nn_ * 16 + l15] = g[r];
            }
        }
        __syncthreads();
        // ---- phase B2: vec conv assembly -> c_sh[512:576] (incl. zero pad) ----
        #pragma unroll
        for (int i = 0; i < 4; ++i) {
            int task = t + i * 256;                // 0..1023
            int vvv = task >> 4, nl = task & 15;
            unsigned short res = 0;
            if (vvv < 24) {
                int c = vvv / 3, s = vvv - c * 3;
                res = f2bf(fmaxf(G_sh[(nl * 3 + s) * 52 + c], 0.f));
            } else if (vvv < 40) {
                int u = vvv - 24, c = u >> 1, s = u & 1;
                float val = G_sh[(nl * 3 + s) * 52 + 8 + 2 * c]
                          + G_sh[(nl * 3 + s + 1) * 52 + 8 + 2 * c + 1];
                res = f2bf(fmaxf(val, 0.f));
            } else if (vvv < 48) {
                int c = vvv - 40;
                float val = G_sh[(nl * 3 + 0) * 52 + 24 + 3 * c]
                          + G_sh[(nl * 3 + 1) * 52 + 24 + 3 * c + 1]
                          + G_sh[(nl * 3 + 2) * 52 + 24 + 3 * c + 2];
                res = f2bf(fmaxf(val, 0.f));
            }
            c_sh[nl * 584 + 512 + vvv] = res;
        }
        __syncthreads();
        // ---- phase C: out = relu(c[16,576] @ Wf + bf) ----
        {
            f32x4 acc; acc.x = 0; acc.y = 0; acc.z = 0; acc.w = 0;
            const unsigned short* ap = &c_sh[l15 * 584 + quad * 8];
            #pragma unroll
            for (int ks = 0; ks < 18; ++ks) {
                bf16x8 a = *(const bf16x8*)(ap + ks * 32);
                acc = __builtin_amdgcn_mfma_f32_16x16x32_bf16(a, wff[ks], acc, 0, 0, 0);
            }
            float* outT = out + (size_t)type * NN * 64;
            #pragma unroll
            for (int r = 0; r < 4; ++r) {
                int node = nodeBase + quad * 4 + r;
                if (node < NN) outT[(size_t)node * 64 + cw] = fmaxf(acc[r] + bfb, 0.f);
            }
        }
    }
}

// ---------------------------------------------------------------------------
extern "C" void kernel_launch(void* const* d_in, const int* in_sizes, int n_in,
                              void* d_out, int out_size, void* d_ws, size_t ws_size,
                              hipStream_t stream)
{
    const float* eu = (const float*)d_in[0];
    const float* ei = (const float*)d_in[1];
    const float* et = (const float*)d_in[2];
    const float* ew = (const float*)d_in[3];
    const int* u_iw_j = (const int*)d_in[4];
    const int* u_iw_w = (const int*)d_in[5];
    const int* u_tw_j = (const int*)d_in[6];
    const int* u_tw_w = (const int*)d_in[7];
    const int* i_uw_j = (const int*)d_in[8];
    const int* i_uw_w = (const int*)d_in[9];
    const int* i_tw_j = (const int*)d_in[10];
    const int* i_tw_w = (const int*)d_in[11];
    const int* t_uw_j = (const int*)d_in[12];
    const int* t_uw_w = (const int*)d_in[13];
    const int* t_iw_j = (const int*)d_in[14];
    const int* t_iw_w = (const int*)d_in[15];
    const float* W1_user = (const float*)d_in[16];
    const float* W2_user = (const float*)d_in[17];
    const float* b_user  = (const float*)d_in[18];
    const float* v_user  = (const float*)d_in[19];
    const float* W1_item = (const float*)d_in[20];
    const float* W2_item = (const float*)d_in[21];
    const float* b_item  = (const float*)d_in[22];
    const float* v_item  = (const float*)d_in[23];
    const float* W1_tag  = (const float*)d_in[24];
    const float* W2_tag  = (const float*)d_in[25];
    const float* b_tag   = (const float*)d_in[26];
    const float* v_tag   = (const float*)d_in[27];
    const float* U    = (const float*)d_in[28];
    const float* q    = (const float*)d_in[29];
    const float* p    = (const float*)d_in[30];
    const float* Wbit = (const float*)d_in[31];
    const float* Wv1  = (const float*)d_in[32];
    const float* Wv2  = (const float*)d_in[33];
    const float* Wv3  = (const float*)d_in[34];
    const float* Wf   = (const float*)d_in[35];
    const float* bfv  = (const float*)d_in[36];
    float* out = (float*)d_out;

    // ---- workspace: gwB 38.4MB | preB 19.2MB | JE 19.2MB | ao 38.4MB ----
    const size_t NV = (size_t)NN * 64;
    unsigned* gwB  = (unsigned*)d_ws;                        // E*32 uints
    unsigned* preB = gwB + (size_t)EE * 32;                  // 6 * N*32 uints
    uint2*    JE   = (uint2*)(preB + (size_t)6 * NN * 32);   // 3 * N*32 uint2
    float*    ao   = (float*)(JE + (size_t)3 * NN * 32);     // 6 * N*64 floats

    const dim3 blk(256);
    const size_t P = (size_t)NN * 32;

    ngemm_kernel<<<dim3(NT, 9), blk, 0, stream>>>(
        eu, ei, et, W1_user, W1_item, W1_tag, W2_user, W2_item, W2_tag,
        b_user, b_item, b_tag, preB, JE);

    // --- item group ---
    egemm_kernel<<<EE / 16, blk, 0, stream>>>(ew, W1_item + 4096, gwB);
    atten1_kernel<<<dim3(NN / 4, 2), blk, 0, stream>>>(
        preB + 0 * P, preB + 5 * P, gwB, JE + (size_t)1 * NN * 32,
        v_item, v_item, u_iw_j, u_iw_w, t_iw_j, t_iw_w, ao + 0 * NV, ao + 5 * NV);
    // --- tag group ---
    egemm_kernel<<<EE / 16, blk, 0, stream>>>(ew, W1_tag + 4096, gwB);
    atten1_kernel<<<dim3(NN / 4, 2), blk, 0, stream>>>(
        preB + 1 * P, preB + 3 * P, gwB, JE + (size_t)2 * NN * 32,
        v_tag, v_tag, u_tw_j, u_tw_w, i_tw_j, i_tw_w, ao + 1 * NV, ao + 3 * NV);
    // --- user group ---
    egemm_kernel<<<EE / 16, blk, 0, stream>>>(ew, W1_user + 4096, gwB);
    atten1_kernel<<<dim3(NN / 4, 2), blk, 0, stream>>>(
        preB + 2 * P, preB + 4 * P, gwB, JE + (size_t)0 * NN * 32,
        v_user, v_user, i_uw_j, i_uw_w, t_uw_j, t_uw_w, ao + 2 * NV, ao + 4 * NV);

    // --- fused tail (all 3 types) ---
    tail_kernel<<<dim3(256, 3), blk, 0, stream>>>(
        eu, ao + 0 * NV, ao + 1 * NV,
        ao + 2 * NV, ei, ao + 3 * NV,
        ao + 4 * NV, ao + 5 * NV, et,
        U, q, p, Wbit, Wv1, Wv2, Wv3, Wf, bfv, out);
}

// Round 3
// 492.929 us; speedup vs baseline: 2.9768x; 1.9060x over previous
//
#include <hip/hip_runtime.h>
#include <math.h>

#define NN 25000
#define EE 300000
#define NT 1563          // ceil(25000/16)   (tail tiles)
#define NT64 391         // ceil(25000/64)   (ngemm tiles)
#define ET64 4688        // ceil(300000/64)  (egemm tiles)

typedef __attribute__((ext_vector_type(8))) short bf16x8;
typedef __attribute__((ext_vector_type(4))) float f32x4;

__device__ __forceinline__ unsigned short f2bf(float f) {
    union { float f; unsigned u; } a; a.f = f;
    unsigned r = (a.u + 0x7fffu + ((a.u >> 16) & 1u)) >> 16;   // RNE
    return (unsigned short)r;
}
__device__ __forceinline__ unsigned pack2(float lo, float hi) {
    return (unsigned)f2bf(lo) | ((unsigned)f2bf(hi) << 16);
}
__device__ __forceinline__ float bflo(unsigned p) {
    union { unsigned u; float f; } a; a.u = p << 16; return a.f;
}
__device__ __forceinline__ float bfhi(unsigned p) {
    union { unsigned u; float f; } a; a.u = p & 0xffff0000u; return a.f;
}

// ---------------------------------------------------------------------------
// egemm: gwB[g] = bf16( ew[E,64] @ W1g[64:128,:] )  for g in {user,item,tag}
// MFMA 16x16x32; 64-row tile/block; all 3 weight B-frags register-resident.
// ---------------------------------------------------------------------------
__global__ __launch_bounds__(256) void egemm_kernel(
    const float* __restrict__ ew,
    const float* __restrict__ Wu, const float* __restrict__ Wi, const float* __restrict__ Wt,
    unsigned* __restrict__ gwB)   // 3 tables of E*32 uints (bf16 pairs)
{
    __shared__ __align__(16) unsigned short stA[64 * 72];
    __shared__ __align__(16) float cS[64 * 68];
    const int t = threadIdx.x;
    const int lane = t & 63, wv = t >> 6;
    const int l15 = lane & 15, quad = lane >> 4;
    const int cw = wv * 16 + l15;                 // this wave's output col

    const float* Ws[3] = { Wu, Wi, Wt };
    bf16x8 bf[3][2];
    #pragma unroll
    for (int w = 0; w < 3; ++w)
        #pragma unroll
        for (int ks = 0; ks < 2; ++ks)
            #pragma unroll
            for (int j = 0; j < 8; ++j)
                bf[w][ks][j] = (short)f2bf(Ws[w][(ks * 32 + quad * 8 + j) * 64 + cw]);

    const int rowBase = blockIdx.x * 64;
    #pragma unroll
    for (int i = 0; i < 4; ++i) {
        int idx = t + i * 256;                    // 0..1023
        int row = idx >> 4, cg = idx & 15;
        int gr = rowBase + row;
        float4 v4 = (gr < EE) ? *(const float4*)(ew + (size_t)gr * 64 + cg * 4)
                              : make_float4(0.f, 0.f, 0.f, 0.f);
        uint2 pk = { pack2(v4.x, v4.y), pack2(v4.z, v4.w) };
        *(uint2*)&stA[row * 72 + cg * 4] = pk;
    }
    __syncthreads();
    bf16x8 af[4][2];
    #pragma unroll
    for (int m = 0; m < 4; ++m)
        #pragma unroll
        for (int ks = 0; ks < 2; ++ks)
            af[m][ks] = *(const bf16x8*)&stA[(m * 16 + l15) * 72 + ks * 32 + quad * 8];

    #pragma unroll
    for (int w = 0; w < 3; ++w) {
        if (w) __syncthreads();
        f32x4 acc[4];
        #pragma unroll
        for (int m = 0; m < 4; ++m) {
            acc[m].x = 0; acc[m].y = 0; acc[m].z = 0; acc[m].w = 0;
            #pragma unroll
            for (int ks = 0; ks < 2; ++ks)
                acc[m] = __builtin_amdgcn_mfma_f32_16x16x32_bf16(af[m][ks], bf[w][ks], acc[m], 0, 0, 0);
            #pragma unroll
            for (int r = 0; r < 4; ++r)
                cS[(m * 16 + quad * 4 + r) * 68 + cw] = acc[m][r];
        }
        __syncthreads();
        unsigned* outg = gwB + (size_t)w * EE * 32;
        #pragma unroll
        for (int i = 0; i < 2; ++i) {
            int task = t + i * 256;               // 0..511
            int row = task >> 3, seg = task & 7;
            int gr = rowBase + row;
            if (gr < EE) {
                float4 a = *(const float4*)&cS[row * 68 + seg * 8];
                float4 b = *(const float4*)&cS[row * 68 + seg * 8 + 4];
                uint4 pk = { pack2(a.x, a.y), pack2(a.z, a.w),
                             pack2(b.x, b.y), pack2(b.z, b.w) };
                *(uint4*)(outg + (size_t)gr * 32 + seg * 4) = pk;
            }
        }
    }
}

// ---------------------------------------------------------------------------
// ngemm: grid.y = source type (eu,ei,et). Per 64-row tile computes
//   preA = X@Wa + ba, preBt = X@Wb + bb  (bf16 pairs)
//   JE   = interleave( X@W2 bf16 pairs , X bf16 pairs )
// ---------------------------------------------------------------------------
__global__ __launch_bounds__(256) void ngemm_kernel(
    const float* __restrict__ eu, const float* __restrict__ ei, const float* __restrict__ et,
    const float* __restrict__ W1u, const float* __restrict__ W1i, const float* __restrict__ W1t,
    const float* __restrict__ W2u, const float* __restrict__ W2i, const float* __restrict__ W2t,
    const float* __restrict__ bu, const float* __restrict__ bi, const float* __restrict__ bt,
    unsigned* __restrict__ preB, uint2* __restrict__ JE)
{
    __shared__ __align__(16) unsigned short stA[64 * 72];
    __shared__ __align__(16) float cS[64 * 68];
    const int t = threadIdx.x;
    const int lane = t & 63, wv = t >> 6;
    const int l15 = lane & 15, quad = lane >> 4;
    const int cw = wv * 16 + l15;
    const int y = blockIdx.y;

    const float* X; const float* Wa; const float* Wb; const float* W2;
    const float* ba; const float* bb; int oa, ob;
    switch (y) {
        case 0:  X = eu; Wa = W1i; ba = bi; oa = 0; Wb = W1t; bb = bt; ob = 1; W2 = W2u; break;
        case 1:  X = ei; Wa = W1u; ba = bu; oa = 2; Wb = W1t; bb = bt; ob = 3; W2 = W2i; break;
        default: X = et; Wa = W1u; ba = bu; oa = 4; Wb = W1i; bb = bi; ob = 5; W2 = W2t; break;
    }
    const float* Ws[3] = { Wa, Wb, W2 };
    const float bias_cw[3] = { ba[cw], bb[cw], 0.f };
    bf16x8 bf[3][2];
    #pragma unroll
    for (int w = 0; w < 3; ++w)
        #pragma unroll
        for (int ks = 0; ks < 2; ++ks)
            #pragma unroll
            for (int j = 0; j < 8; ++j)
                bf[w][ks][j] = (short)f2bf(Ws[w][(ks * 32 + quad * 8 + j) * 64 + cw]);

    const int rowBase = blockIdx.x * 64;
    #pragma unroll
    for (int i = 0; i < 4; ++i) {
        int idx = t + i * 256;
        int row = idx >> 4, cg = idx & 15;
        int gr = rowBase + row;
        float4 v4 = (gr < NN) ? *(const float4*)(X + (size_t)gr * 64 + cg * 4)
                              : make_float4(0.f, 0.f, 0.f, 0.f);
        uint2 pk = { pack2(v4.x, v4.y), pack2(v4.z, v4.w) };
        *(uint2*)&stA[row * 72 + cg * 4] = pk;
    }
    __syncthreads();
    bf16x8 af[4][2];
    #pragma unroll
    for (int m = 0; m < 4; ++m)
        #pragma unroll
        for (int ks = 0; ks < 2; ++ks)
            af[m][ks] = *(const bf16x8*)&stA[(m * 16 + l15) * 72 + ks * 32 + quad * 8];

    #pragma unroll
    for (int w = 0; w < 3; ++w) {
        if (w) __syncthreads();
        f32x4 acc[4];
        #pragma unroll
        for (int m = 0; m < 4; ++m) {
            acc[m].x = 0; acc[m].y = 0; acc[m].z = 0; acc[m].w = 0;
            #pragma unroll
            for (int ks = 0; ks < 2; ++ks)
                acc[m] = __builtin_amdgcn_mfma_f32_16x16x32_bf16(af[m][ks], bf[w][ks], acc[m], 0, 0, 0);
            #pragma unroll
            for (int r = 0; r < 4; ++r)
                cS[(m * 16 + quad * 4 + r) * 68 + cw] = acc[m][r] + bias_cw[w];
        }
        __syncthreads();
        #pragma unroll
        for (int i = 0; i < 2; ++i) {
            int task = t + i * 256;
            int row = task >> 3, seg = task & 7;
            int gr = rowBase + row;
            if (gr >= NN) continue;
            float4 a = *(const float4*)&cS[row * 68 + seg * 8];
            float4 b = *(const float4*)&cS[row * 68 + seg * 8 + 4];
            if (w < 2) {
                int oi = (w == 0) ? oa : ob;
                uint4 pk = { pack2(a.x, a.y), pack2(a.z, a.w),
                             pack2(b.x, b.y), pack2(b.z, b.w) };
                *(uint4*)(preB + ((size_t)oi * NN + gr) * 32 + seg * 4) = pk;
            } else {
                uint4 ejp = *(const uint4*)&stA[row * 72 + seg * 8];
                uint4 p1 = { pack2(a.x, a.y), ejp.x, pack2(a.z, a.w), ejp.y };
                uint4 p2 = { pack2(b.x, b.y), ejp.z, pack2(b.z, b.w), ejp.w };
                uint4* dst = (uint4*)(JE + (size_t)y * NN * 32 + (size_t)gr * 32 + seg * 4);
                dst[0] = p1; dst[1] = p2;
            }
        }
    }
}

// ---------------------------------------------------------------------------
// atten1: all 6 attention aggregations in one dispatch (grid.y selects).
// bf16 tables, pair-packed lanes. Output bf16 pairs (aoB).
// ---------------------------------------------------------------------------
__global__ __launch_bounds__(256) void atten1_kernel(
    const unsigned* __restrict__ preB, const unsigned* __restrict__ gwB,
    const uint2* __restrict__ JE,
    const float* __restrict__ vu, const float* __restrict__ vi, const float* __restrict__ vt,
    const int* __restrict__ u_iw_j, const int* __restrict__ u_iw_w,
    const int* __restrict__ u_tw_j, const int* __restrict__ u_tw_w,
    const int* __restrict__ i_uw_j, const int* __restrict__ i_uw_w,
    const int* __restrict__ i_tw_j, const int* __restrict__ i_tw_w,
    const int* __restrict__ t_uw_j, const int* __restrict__ t_uw_w,
    const int* __restrict__ t_iw_j, const int* __restrict__ t_iw_w,
    unsigned* __restrict__ aoB)
{
    const int y = blockIdx.y;
    const int* Vj; const int* Vw; const float* v; int g;
    switch (y) {
        case 0:  Vj = u_iw_j; Vw = u_iw_w; v = vi; g = 1; break;
        case 1:  Vj = u_tw_j; Vw = u_tw_w; v = vt; g = 2; break;
        case 2:  Vj = i_uw_j; Vw = i_uw_w; v = vu; g = 0; break;
        case 3:  Vj = i_tw_j; Vw = i_tw_w; v = vt; g = 2; break;
        case 4:  Vj = t_uw_j; Vw = t_uw_w; v = vu; g = 0; break;
        default: Vj = t_iw_j; Vw = t_iw_w; v = vi; g = 1; break;
    }
    const unsigned* pre = preB + (size_t)y * NN * 32;
    const unsigned* gw  = gwB + (size_t)g * EE * 32;
    const uint2*    je  = JE  + (size_t)g * NN * 32;
    unsigned*       out = aoB + (size_t)y * NN * 32;

    const int lane = threadIdx.x & 63;
    const int n = blockIdx.x * 4 + (threadIdx.x >> 6);
    const int half = lane >> 5, pl = lane & 31;

    unsigned prep = pre[(size_t)n * 32 + pl];
    const float p0 = bflo(prep), p1 = bfhi(prep);
    const float2 vp = ((const float2*)v)[pl];

    float xk[8]; unsigned ejp[8];
    #pragma unroll
    for (int i = 0; i < 8; ++i) {
        int k = 2 * i + half;
        int w = Vw[n * 16 + k];
        int j = Vj[n * 16 + k];
        unsigned gp = (w > 0) ? gw[(size_t)(w - 1) * 32 + pl] : 0u;
        uint2 jev = (j > 0) ? je[(size_t)(j - 1) * 32 + pl] : make_uint2(0u, 0u);
        ejp[i] = jev.y;
        float x = fmaxf(p0 + bflo(gp) + bflo(jev.x), 0.f) * vp.x
                + fmaxf(p1 + bfhi(gp) + bfhi(jev.x), 0.f) * vp.y;
        x += __shfl_xor(x, 1, 64);  x += __shfl_xor(x, 2, 64);
        x += __shfl_xor(x, 4, 64);  x += __shfl_xor(x, 8, 64);
        x += __shfl_xor(x, 16, 64);
        xk[i] = x;
    }
    float m = xk[0];
    #pragma unroll
    for (int i = 1; i < 8; ++i) m = fmaxf(m, xk[i]);
    m = fmaxf(m, __shfl_xor(m, 32, 64));
    float s = 0.f;
    #pragma unroll
    for (int i = 0; i < 8; ++i) { xk[i] = __expf(xk[i] - m); s += xk[i]; }
    s += __shfl_xor(s, 32, 64);
    const float inv = 1.f / s;
    float a0 = 0.f, a1 = 0.f;
    #pragma unroll
    for (int i = 0; i < 8; ++i) {
        float wgt = xk[i] * inv;
        a0 = fmaf(wgt, bflo(ejp[i]), a0);
        a1 = fmaf(wgt, bfhi(ejp[i]), a1);
    }
    a0 += __shfl_xor(a0, 32, 64);
    a1 += __shfl_xor(a1, 32, 64);
    if (half == 0) out[(size_t)n * 32 + pl] = pack2(a0, a1);
}

// ---------------------------------------------------------------------------
// tail: atten2 + convs + final linear, all MFMA (16x16x32 bf16).
// ao inputs read directly as bf16 pairs; the per-type raw input is fp32.
// ---------------------------------------------------------------------------
__global__ __launch_bounds__(256, 3) void tail_kernel(
    const float* __restrict__ eu, const float* __restrict__ ei, const float* __restrict__ et,
    const unsigned* __restrict__ aoB,
    const float* __restrict__ U, const float* __restrict__ q, const float* __restrict__ p,
    const float* __restrict__ Wbit, const float* __restrict__ Wv1,
    const float* __restrict__ Wv2, const float* __restrict__ Wv3,
    const float* __restrict__ Wf, const float* __restrict__ bfv,
    float* __restrict__ out)
{
    __shared__ __align__(16) unsigned short uitA[48 * 72];
    __shared__ __align__(16) unsigned short eNA[48 * 72];
    __shared__ __align__(16) unsigned short wcf[6 * 64 * 8];
    __shared__ __align__(16) unsigned short c_sh[16 * 584];
    __shared__ float G_sh[48 * 52];
    __shared__ float xpart[4 * 48];
    __shared__ float bcoef[16 * 4];

    const int t = threadIdx.x;
    const int lane = t & 63;
    const int wv = t >> 6;
    const int l15 = lane & 15;
    const int quad = lane >> 4;
    const int type = blockIdx.y;
    const float* xf = (type == 0) ? eu : (type == 1) ? ei : et;
    const int cw = wv * 16 + l15;
    const float qv = q[cw], pv = p[cw], bfb = bfv[cw];

    float wb[8][3];
    #pragma unroll
    for (int c = 0; c < 8; ++c)
        #pragma unroll
        for (int s = 0; s < 3; ++s) wb[c][s] = Wbit[c * 3 + s];

    bf16x8 ufrag[2];
    #pragma unroll
    for (int ks = 0; ks < 2; ++ks)
        #pragma unroll
        for (int j = 0; j < 8; ++j) {
            int f = ks * 32 + quad * 8 + j;
            ufrag[ks][j] = (short)f2bf(U[f * 64 + cw]);
        }
    bf16x8 wff[18];
    #pragma unroll
    for (int ks = 0; ks < 18; ++ks)
        #pragma unroll
        for (int j = 0; j < 8; ++j) {
            int k = ks * 32 + quad * 8 + j;
            float w = (k < 560) ? Wf[(size_t)k * 64 + cw] : 0.f;
            wff[ks][j] = (short)f2bf(w);
        }
    for (int slot = t; slot < 384; slot += 256) {
        int fi = slot >> 6, l = slot & 63;
        int nt_ = fi >> 1, ks = fi & 1;
        int r = nt_ * 16 + (l & 15);
        unsigned short vals[8];
        #pragma unroll
        for (int j = 0; j < 8; ++j) {
            int f = ks * 32 + (l >> 4) * 8 + j;
            float wv_;
            if (r < 8)       wv_ = Wv1[r * 64 + f];
            else if (r < 24) { int u = r - 8;  wv_ = Wv2[(u >> 1) * 128 + (u & 1) * 64 + f]; }
            else             { int u = r - 24; wv_ = Wv3[(u / 3) * 192 + (u % 3) * 64 + f]; }
            vals[j] = f2bf(wv_);
        }
        uint4 pk = { (unsigned)vals[0] | ((unsigned)vals[1] << 16),
                     (unsigned)vals[2] | ((unsigned)vals[3] << 16),
                     (unsigned)vals[4] | ((unsigned)vals[5] << 16),
                     (unsigned)vals[6] | ((unsigned)vals[7] << 16) };
        *(uint4*)&wcf[slot * 8] = pk;
    }

    for (int tile = blockIdx.x; tile < NT; tile += gridDim.x) {
        const int nodeBase = tile * 16;
        __syncthreads();
        #pragma unroll
        for (int i = 0; i < 3; ++i) {
            int idx = t + i * 256;
            int row = idx >> 4, cg = idx & 15;
            int nl = row / 3, s = row - nl * 3;
            int n = nodeBase + nl;
            uint2 pk;
            if (s == type) {
                float4 v4 = (n < NN) ? *(const float4*)(xf + (size_t)n * 64 + cg * 4)
                                     : make_float4(0.f, 0.f, 0.f, 0.f);
                pk.x = pack2(v4.x, v4.y); pk.y = pack2(v4.z, v4.w);
            } else {
                int aoidx = (type == 0) ? (s - 1)
                          : (type == 1) ? ((s == 0) ? 2 : 3)
                                        : ((s == 0) ? 4 : 5);
                pk = (n < NN) ? *(const uint2*)(aoB + ((size_t)aoidx * NN + n) * 32 + cg * 2)
                              : make_uint2(0u, 0u);
            }
            *(uint2*)&uitA[row * 72 + cg * 4] = pk;
        }
        __syncthreads();
        {
            f32x4 av[3];
            #pragma unroll
            for (int mt = 0; mt < 3; ++mt) { av[mt].x = 0; av[mt].y = 0; av[mt].z = 0; av[mt].w = 0; }
            #pragma unroll
            for (int mt = 0; mt < 3; ++mt)
                #pragma unroll
                for (int ks = 0; ks < 2; ++ks) {
                    bf16x8 a = *(const bf16x8*)&uitA[(mt * 16 + l15) * 72 + ks * 32 + quad * 8];
                    av[mt] = __builtin_amdgcn_mfma_f32_16x16x32_bf16(a, ufrag[ks], av[mt], 0, 0, 0);
                }
            #pragma unroll
            for (int mt = 0; mt < 3; ++mt)
                #pragma unroll
                for (int r = 0; r < 4; ++r) {
                    float val = fmaxf(av[mt][r] + qv, 0.f) * pv;
                    val += __shfl_xor(val, 1, 64); val += __shfl_xor(val, 2, 64);
                    val += __shfl_xor(val, 4, 64); val += __shfl_xor(val, 8, 64);
                    if (l15 == 0) xpart[wv * 48 + mt * 16 + quad * 4 + r] = val;
                }
        }
        __syncthreads();
        if (t < 16) {
            float xv[3];
            #pragma unroll
            for (int s = 0; s < 3; ++s)
                xv[s] = xpart[t * 3 + s] + xpart[48 + t * 3 + s]
                      + xpart[96 + t * 3 + s] + xpart[144 + t * 3 + s];
            float mm = fmaxf(xv[0], fmaxf(xv[1], xv[2]));
            float e0 = __expf(xv[0] - mm), e1 = __expf(xv[1] - mm), e2 = __expf(xv[2] - mm);
            float inv = 1.f / (e0 + e1 + e2);
            bcoef[t * 4 + 0] = e0 * inv; bcoef[t * 4 + 1] = e1 * inv; bcoef[t * 4 + 2] = e2 * inv;
        }
        __syncthreads();
        #pragma unroll
        for (int i = 0; i < 2; ++i) {
            int task = t + i * 256;
            int nl = task >> 5, fp = task & 31;
            float b0 = bcoef[nl * 4], b1 = bcoef[nl * 4 + 1], b2 = bcoef[nl * 4 + 2];
            unsigned u0 = *(const unsigned*)&uitA[(nl * 3 + 0) * 72 + fp * 2];
            unsigned u1 = *(const unsigned*)&uitA[(nl * 3 + 1) * 72 + fp * 2];
            unsigned u2 = *(const unsigned*)&uitA[(nl * 3 + 2) * 72 + fp * 2];
            float e0l = b0 * bflo(u0), e0h = b0 * bfhi(u0);
            float e1l = b1 * bflo(u1), e1h = b1 * bfhi(u1);
            float e2l = b2 * bflo(u2), e2h = b2 * bfhi(u2);
            *(unsigned*)&eNA[(nl * 3 + 0) * 72 + fp * 2] = pack2(e0l, e0h);
            *(unsigned*)&eNA[(nl * 3 + 1) * 72 + fp * 2] = pack2(e1l, e1h);
            *(unsigned*)&eNA[(nl * 3 + 2) * 72 + fp * 2] = pack2(e2l, e2h);
            #pragma unroll
            for (int c = 0; c < 8; ++c) {
                float lo = fmaxf(wb[c][0] * e0l + wb[c][1] * e1l + wb[c][2] * e2l, 0.f);
                float hi = fmaxf(wb[c][0] * e0h + wb[c][1] * e1h + wb[c][2] * e2h, 0.f);
                *(unsigned*)&c_sh[nl * 584 + c * 64 + fp * 2] = pack2(lo, hi);
            }
        }
        __syncthreads();
        #pragma unroll
        for (int pi = 0; pi < 3; ++pi) {
            int pr = wv + pi * 4;
            if (pr < 9) {
                int mm = pr / 3, nn_ = pr - mm * 3;
                f32x4 g; g.x = 0; g.y = 0; g.z = 0; g.w = 0;
                #pragma unroll
                for (int ks = 0; ks < 2; ++ks) {
                    bf16x8 a = *(const bf16x8*)&eNA[(mm * 16 + l15) * 72 + ks * 32 + quad * 8];
                    bf16x8 b = *(const bf16x8*)&wcf[((nn_ * 2 + ks) * 64 + lane) * 8];
                    g = __builtin_amdgcn_mfma_f32_16x16x32_bf16(a, b, g, 0, 0, 0);
                }
                #pragma unroll
                for (int r = 0; r < 4; ++r)
                    G_sh[(mm * 16 + quad * 4 + r) * 52 + nn_ * 16 + l15] = g[r];
            }
        }
        __syncthreads();
        #pragma unroll
        for (int i = 0; i < 4; ++i) {
            int task = t + i * 256;
            int vvv = task >> 4, nl = task & 15;
            unsigned short res = 0;
            if (vvv < 24) {
                int c = vvv / 3, s = vvv - c * 3;
                res = f2bf(fmaxf(G_sh[(nl * 3 + s) * 52 + c], 0.f));
            } else if (vvv < 40) {
                int u = vvv - 24, c = u >> 1, s = u & 1;
                float val = G_sh[(nl * 3 + s) * 52 + 8 + 2 * c]
                          + G_sh[(nl * 3 + s + 1) * 52 + 8 + 2 * c + 1];
                res = f2bf(fmaxf(val, 0.f));
            } else if (vvv < 48) {
                int c = vvv - 40;
                float val = G_sh[(nl * 3 + 0) * 52 + 24 + 3 * c]
                          + G_sh[(nl * 3 + 1) * 52 + 24 + 3 * c + 1]
                          + G_sh[(nl * 3 + 2) * 52 + 24 + 3 * c + 2];
                res = f2bf(fmaxf(val, 0.f));
            }
            c_sh[nl * 584 + 512 + vvv] = res;
        }
        __syncthreads();
        {
            f32x4 acc; acc.x = 0; acc.y = 0; acc.z = 0; acc.w = 0;
            const unsigned short* ap = &c_sh[l15 * 584 + quad * 8];
            #pragma unroll
            for (int ks = 0; ks < 18; ++ks) {
                bf16x8 a = *(const bf16x8*)(ap + ks * 32);
                acc = __builtin_amdgcn_mfma_f32_16x16x32_bf16(a, wff[ks], acc, 0, 0, 0);
            }
            float* outT = out + (size_t)type * NN * 64;
            #pragma unroll
            for (int r = 0; r < 4; ++r) {
                int node = nodeBase + quad * 4 + r;
                if (node < NN) outT[(size_t)node * 64 + cw] = fmaxf(acc[r] + bfb, 0.f);
            }
        }
    }
}

// ---------------------------------------------------------------------------
extern "C" void kernel_launch(void* const* d_in, const int* in_sizes, int n_in,
                              void* d_out, int out_size, void* d_ws, size_t ws_size,
                              hipStream_t stream)
{
    const float* eu = (const float*)d_in[0];
    const float* ei = (const float*)d_in[1];
    const float* et = (const float*)d_in[2];
    const float* ew = (const float*)d_in[3];
    const int* u_iw_j = (const int*)d_in[4];
    const int* u_iw_w = (const int*)d_in[5];
    const int* u_tw_j = (const int*)d_in[6];
    const int* u_tw_w = (const int*)d_in[7];
    const int* i_uw_j = (const int*)d_in[8];
    const int* i_uw_w = (const int*)d_in[9];
    const int* i_tw_j = (const int*)d_in[10];
    const int* i_tw_w = (const int*)d_in[11];
    const int* t_uw_j = (const int*)d_in[12];
    const int* t_uw_w = (const int*)d_in[13];
    const int* t_iw_j = (const int*)d_in[14];
    const int* t_iw_w = (const int*)d_in[15];
    const float* W1_user = (const float*)d_in[16];
    const float* W2_user = (const float*)d_in[17];
    const float* b_user  = (const float*)d_in[18];
    const float* v_user  = (const float*)d_in[19];
    const float* W1_item = (const float*)d_in[20];
    const float* W2_item = (const float*)d_in[21];
    const float* b_item  = (const float*)d_in[22];
    const float* v_item  = (const float*)d_in[23];
    const float* W1_tag  = (const float*)d_in[24];
    const float* W2_tag  = (const float*)d_in[25];
    const float* b_tag   = (const float*)d_in[26];
    const float* v_tag   = (const float*)d_in[27];
    const float* U    = (const float*)d_in[28];
    const float* q    = (const float*)d_in[29];
    const float* p    = (const float*)d_in[30];
    const float* Wbit = (const float*)d_in[31];
    const float* Wv1  = (const float*)d_in[32];
    const float* Wv2  = (const float*)d_in[33];
    const float* Wv3  = (const float*)d_in[34];
    const float* Wf   = (const float*)d_in[35];
    const float* bfv  = (const float*)d_in[36];
    float* out = (float*)d_out;

    // ---- workspace (172.8 MB total, same peak as round-0 which passed) ----
    // gwB: 3 x E*32 uints = 115.2 MB | preB: 6 x N*32 = 19.2 MB
    // JE:  3 x N*32 uint2 = 19.2 MB  | aoB: 6 x N*32 = 19.2 MB
    unsigned* gwB  = (unsigned*)d_ws;
    unsigned* preB = gwB + (size_t)3 * EE * 32;
    uint2*    JE   = (uint2*)(preB + (size_t)6 * NN * 32);
    unsigned* aoB  = (unsigned*)(JE + (size_t)3 * NN * 32);

    const dim3 blk(256);

    ngemm_kernel<<<dim3(NT64, 3), blk, 0, stream>>>(
        eu, ei, et, W1_user, W1_item, W1_tag, W2_user, W2_item, W2_tag,
        b_user, b_item, b_tag, preB, JE);

    egemm_kernel<<<ET64, blk, 0, stream>>>(
        ew, W1_user + 4096, W1_item + 4096, W1_tag + 4096, gwB);

    atten1_kernel<<<dim3(NN / 4, 6), blk, 0, stream>>>(
        preB, gwB, JE, v_user, v_item, v_tag,
        u_iw_j, u_iw_w, u_tw_j, u_tw_w, i_uw_j, i_uw_w,
        i_tw_j, i_tw_w, t_uw_j, t_uw_w, t_iw_j, t_iw_w, aoB);

    tail_kernel<<<dim3(256, 3), blk, 0, stream>>>(
        eu, ei, et, aoB,
        U, q, p, Wbit, Wv1, Wv2, Wv3, Wf, bfv, out);
}

// Round 4
// 465.931 us; speedup vs baseline: 3.1493x; 1.0579x over previous
//
#include <hip/hip_runtime.h>
#include <math.h>

#define NN 25000
#define EE 300000
#define NT 1563          // ceil(25000/16)   (tail tiles)
#define NT64 391         // ceil(25000/64)   (ngemm tiles)
#define ET64 4688        // ceil(300000/64)  (egemm tiles)

typedef __attribute__((ext_vector_type(8))) short bf16x8;
typedef __attribute__((ext_vector_type(4))) float f32x4;
typedef __attribute__((ext_vector_type(2))) float f32x2;

__device__ __forceinline__ unsigned short f2bf(float f) {
    union { float f; unsigned u; } a; a.f = f;
    unsigned r = (a.u + 0x7fffu + ((a.u >> 16) & 1u)) >> 16;   // RNE
    return (unsigned short)r;
}
__device__ __forceinline__ unsigned pack2(float lo, float hi) {
    return (unsigned)f2bf(lo) | ((unsigned)f2bf(hi) << 16);
}
__device__ __forceinline__ float bflo(unsigned p) {
    union { unsigned u; float f; } a; a.u = p << 16; return a.f;
}
__device__ __forceinline__ float bfhi(unsigned p) {
    union { unsigned u; float f; } a; a.u = p & 0xffff0000u; return a.f;
}
// pack 4 floats -> 4 fp8(e4m3, HW OCP on gfx950) in one uint
__device__ __forceinline__ unsigned packfp8x4(float a, float b, float c, float d) {
    int v = __builtin_amdgcn_cvt_pk_fp8_f32(a, b, 0, 0);
    v = __builtin_amdgcn_cvt_pk_fp8_f32(c, d, v, 1);
    return (unsigned)v;
}

// ---------------------------------------------------------------------------
// head: fused egemm + ngemm (one dispatch; block role from blockIdx.x).
//  egemm part (blocks [0,ET64)): gw8[g] = fp8( ew @ W1g[64:128,:] ), g=u,i,t
//  ngemm part: per source X in {eu,ei,et}:
//    preB = bf16(X@Wa + ba), bf16(X@Wb + bb)
//    JG   = [ fp8(X@W2) 64B | bf16(X) 128B ]  (192 B rows)
// ---------------------------------------------------------------------------
__global__ __launch_bounds__(256) void head_kernel(
    const float* __restrict__ ew,
    const float* __restrict__ eu, const float* __restrict__ ei, const float* __restrict__ et,
    const float* __restrict__ W1u, const float* __restrict__ W1i, const float* __restrict__ W1t,
    const float* __restrict__ W2u, const float* __restrict__ W2i, const float* __restrict__ W2t,
    const float* __restrict__ bu, const float* __restrict__ bi, const float* __restrict__ bt,
    unsigned char* __restrict__ gw8, unsigned* __restrict__ preB,
    unsigned char* __restrict__ JG)
{
    __shared__ __align__(16) unsigned short stA[64 * 72];
    __shared__ __align__(16) float cS[64 * 68];
    const int t = threadIdx.x;
    const int lane = t & 63, wv = t >> 6;
    const int l15 = lane & 15, quad = lane >> 4;
    const int cw = wv * 16 + l15;                 // this wave's output col
    const int bx = blockIdx.x;

    if (bx < ET64) {
        // ================= egemm role =================
        const float* Ws[3] = { W1u + 4096, W1i + 4096, W1t + 4096 };
        bf16x8 bf[3][2];
        #pragma unroll
        for (int w = 0; w < 3; ++w)
            #pragma unroll
            for (int ks = 0; ks < 2; ++ks)
                #pragma unroll
                for (int j = 0; j < 8; ++j)
                    bf[w][ks][j] = (short)f2bf(Ws[w][(ks * 32 + quad * 8 + j) * 64 + cw]);

        const int rowBase = bx * 64;
        #pragma unroll
        for (int i = 0; i < 4; ++i) {
            int idx = t + i * 256;
            int row = idx >> 4, cg = idx & 15;
            int gr = rowBase + row;
            float4 v4 = (gr < EE) ? *(const float4*)(ew + (size_t)gr * 64 + cg * 4)
                                  : make_float4(0.f, 0.f, 0.f, 0.f);
            uint2 pk = { pack2(v4.x, v4.y), pack2(v4.z, v4.w) };
            *(uint2*)&stA[row * 72 + cg * 4] = pk;
        }
        __syncthreads();
        bf16x8 af[4][2];
        #pragma unroll
        for (int m = 0; m < 4; ++m)
            #pragma unroll
            for (int ks = 0; ks < 2; ++ks)
                af[m][ks] = *(const bf16x8*)&stA[(m * 16 + l15) * 72 + ks * 32 + quad * 8];

        #pragma unroll
        for (int w = 0; w < 3; ++w) {
            if (w) __syncthreads();
            f32x4 acc[4];
            #pragma unroll
            for (int m = 0; m < 4; ++m) {
                acc[m].x = 0; acc[m].y = 0; acc[m].z = 0; acc[m].w = 0;
                #pragma unroll
                for (int ks = 0; ks < 2; ++ks)
                    acc[m] = __builtin_amdgcn_mfma_f32_16x16x32_bf16(af[m][ks], bf[w][ks], acc[m], 0, 0, 0);
                #pragma unroll
                for (int r = 0; r < 4; ++r)
                    cS[(m * 16 + quad * 4 + r) * 68 + cw] = acc[m][r];
            }
            __syncthreads();
            unsigned char* outg = gw8 + (size_t)w * EE * 64;
            #pragma unroll
            for (int i = 0; i < 2; ++i) {
                int task = t + i * 256;               // 0..511
                int row = task >> 3, seg = task & 7;  // seg: 8 feats
                int gr = rowBase + row;
                if (gr < EE) {
                    float4 a = *(const float4*)&cS[row * 68 + seg * 8];
                    float4 b = *(const float4*)&cS[row * 68 + seg * 8 + 4];
                    uint2 pk = { packfp8x4(a.x, a.y, a.z, a.w),
                                 packfp8x4(b.x, b.y, b.z, b.w) };
                    *(uint2*)(outg + (size_t)gr * 64 + seg * 8) = pk;
                }
            }
        }
    } else {
        // ================= ngemm role =================
        const int yy = bx - ET64;
        const int y = yy / NT64;
        const int rowBase = (yy - y * NT64) * 64;
        const float* X; const float* Wa; const float* Wb; const float* W2;
        const float* ba; const float* bb; int oa, ob;
        switch (y) {
            case 0:  X = eu; Wa = W1i; ba = bi; oa = 0; Wb = W1t; bb = bt; ob = 1; W2 = W2u; break;
            case 1:  X = ei; Wa = W1u; ba = bu; oa = 2; Wb = W1t; bb = bt; ob = 3; W2 = W2i; break;
            default: X = et; Wa = W1u; ba = bu; oa = 4; Wb = W1i; bb = bi; ob = 5; W2 = W2t; break;
        }
        const float* Ws[3] = { Wa, Wb, W2 };
        const float bias_cw[3] = { ba[cw], bb[cw], 0.f };
        bf16x8 bf[3][2];
        #pragma unroll
        for (int w = 0; w < 3; ++w)
            #pragma unroll
            for (int ks = 0; ks < 2; ++ks)
                #pragma unroll
                for (int j = 0; j < 8; ++j)
                    bf[w][ks][j] = (short)f2bf(Ws[w][(ks * 32 + quad * 8 + j) * 64 + cw]);

        #pragma unroll
        for (int i = 0; i < 4; ++i) {
            int idx = t + i * 256;
            int row = idx >> 4, cg = idx & 15;
            int gr = rowBase + row;
            float4 v4 = (gr < NN) ? *(const float4*)(X + (size_t)gr * 64 + cg * 4)
                                  : make_float4(0.f, 0.f, 0.f, 0.f);
            uint2 pk = { pack2(v4.x, v4.y), pack2(v4.z, v4.w) };
            *(uint2*)&stA[row * 72 + cg * 4] = pk;
        }
        __syncthreads();
        bf16x8 af[4][2];
        #pragma unroll
        for (int m = 0; m < 4; ++m)
            #pragma unroll
            for (int ks = 0; ks < 2; ++ks)
                af[m][ks] = *(const bf16x8*)&stA[(m * 16 + l15) * 72 + ks * 32 + quad * 8];

        #pragma unroll
        for (int w = 0; w < 3; ++w) {
            if (w) __syncthreads();
            f32x4 acc[4];
            #pragma unroll
            for (int m = 0; m < 4; ++m) {
                acc[m].x = 0; acc[m].y = 0; acc[m].z = 0; acc[m].w = 0;
                #pragma unroll
                for (int ks = 0; ks < 2; ++ks)
                    acc[m] = __builtin_amdgcn_mfma_f32_16x16x32_bf16(af[m][ks], bf[w][ks], acc[m], 0, 0, 0);
                #pragma unroll
                for (int r = 0; r < 4; ++r)
                    cS[(m * 16 + quad * 4 + r) * 68 + cw] = acc[m][r] + bias_cw[w];
            }
            __syncthreads();
            #pragma unroll
            for (int i = 0; i < 2; ++i) {
                int task = t + i * 256;
                int row = task >> 3, seg = task & 7;
                int gr = rowBase + row;
                if (gr >= NN) continue;
                float4 a = *(const float4*)&cS[row * 68 + seg * 8];
                float4 b = *(const float4*)&cS[row * 68 + seg * 8 + 4];
                if (w < 2) {
                    int oi = (w == 0) ? oa : ob;
                    uint4 pk = { pack2(a.x, a.y), pack2(a.z, a.w),
                                 pack2(b.x, b.y), pack2(b.z, b.w) };
                    *(uint4*)(preB + ((size_t)oi * NN + gr) * 32 + seg * 4) = pk;
                } else {
                    unsigned char* dst = JG + ((size_t)y * NN + gr) * 192;
                    uint2 gj = { packfp8x4(a.x, a.y, a.z, a.w),
                                 packfp8x4(b.x, b.y, b.z, b.w) };
                    *(uint2*)(dst + seg * 8) = gj;
                    uint4 ej = *(const uint4*)&stA[row * 72 + seg * 8];
                    *(uint4*)(dst + 64 + seg * 16) = ej;
                }
            }
        }
    }
}

// ---------------------------------------------------------------------------
// atten1: all 6 attention aggregations in one dispatch (grid.y selects).
// gw/gj tables fp8 (HW decode), ej bf16. Output bf16 pairs (aoB).
// ---------------------------------------------------------------------------
__global__ __launch_bounds__(256) void atten1_kernel(
    const unsigned* __restrict__ preB, const unsigned char* __restrict__ gw8,
    const unsigned char* __restrict__ JG,
    const float* __restrict__ vu, const float* __restrict__ vi, const float* __restrict__ vt,
    const int* __restrict__ u_iw_j, const int* __restrict__ u_iw_w,
    const int* __restrict__ u_tw_j, const int* __restrict__ u_tw_w,
    const int* __restrict__ i_uw_j, const int* __restrict__ i_uw_w,
    const int* __restrict__ i_tw_j, const int* __restrict__ i_tw_w,
    const int* __restrict__ t_uw_j, const int* __restrict__ t_uw_w,
    const int* __restrict__ t_iw_j, const int* __restrict__ t_iw_w,
    unsigned* __restrict__ aoB)
{
    const int y = blockIdx.y;
    const int* Vj; const int* Vw; const float* v; int g;
    switch (y) {
        case 0:  Vj = u_iw_j; Vw = u_iw_w; v = vi; g = 1; break;
        case 1:  Vj = u_tw_j; Vw = u_tw_w; v = vt; g = 2; break;
        case 2:  Vj = i_uw_j; Vw = i_uw_w; v = vu; g = 0; break;
        case 3:  Vj = i_tw_j; Vw = i_tw_w; v = vt; g = 2; break;
        case 4:  Vj = t_uw_j; Vw = t_uw_w; v = vu; g = 0; break;
        default: Vj = t_iw_j; Vw = t_iw_w; v = vi; g = 1; break;
    }
    const unsigned* pre = preB + (size_t)y * NN * 32;
    const unsigned char* gw = gw8 + (size_t)g * EE * 64;
    const unsigned char* jg = JG + (size_t)g * NN * 192;
    unsigned*            out = aoB + (size_t)y * NN * 32;

    const int lane = threadIdx.x & 63;
    const int n = blockIdx.x * 4 + (threadIdx.x >> 6);
    const int half = lane >> 5, pl = lane & 31;

    unsigned prep = pre[(size_t)n * 32 + pl];
    const float p0 = bflo(prep), p1 = bfhi(prep);
    const float2 vp = ((const float2*)v)[pl];

    float xk[8]; unsigned ejp[8];
    #pragma unroll
    for (int i = 0; i < 8; ++i) {
        int k = 2 * i + half;
        int w = Vw[n * 16 + k];
        int j = Vj[n * 16 + k];
        unsigned short gp = 0, jp = 0; unsigned ev = 0;
        if (w > 0) gp = *(const unsigned short*)(gw + (size_t)(w - 1) * 64 + pl * 2);
        if (j > 0) {
            const unsigned char* r = jg + (size_t)(j - 1) * 192;
            jp = *(const unsigned short*)(r + pl * 2);
            ev = *(const unsigned*)(r + 64 + pl * 4);
        }
        ejp[i] = ev;
        f32x2 g2 = __builtin_amdgcn_cvt_pk_f32_fp8((int)gp, false);
        f32x2 j2 = __builtin_amdgcn_cvt_pk_f32_fp8((int)jp, false);
        float x = fmaxf(p0 + g2.x + j2.x, 0.f) * vp.x
                + fmaxf(p1 + g2.y + j2.y, 0.f) * vp.y;
        x += __shfl_xor(x, 1, 64);  x += __shfl_xor(x, 2, 64);
        x += __shfl_xor(x, 4, 64);  x += __shfl_xor(x, 8, 64);
        x += __shfl_xor(x, 16, 64);
        xk[i] = x;
    }
    float m = xk[0];
    #pragma unroll
    for (int i = 1; i < 8; ++i) m = fmaxf(m, xk[i]);
    m = fmaxf(m, __shfl_xor(m, 32, 64));
    float s = 0.f;
    #pragma unroll
    for (int i = 0; i < 8; ++i) { xk[i] = __expf(xk[i] - m); s += xk[i]; }
    s += __shfl_xor(s, 32, 64);
    const float inv = 1.f / s;
    float a0 = 0.f, a1 = 0.f;
    #pragma unroll
    for (int i = 0; i < 8; ++i) {
        float wgt = xk[i] * inv;
        a0 = fmaf(wgt, bflo(ejp[i]), a0);
        a1 = fmaf(wgt, bfhi(ejp[i]), a1);
    }
    a0 += __shfl_xor(a0, 32, 64);
    a1 += __shfl_xor(a1, 32, 64);
    if (half == 0) out[(size_t)n * 32 + pl] = pack2(a0, a1);
}

// ---------------------------------------------------------------------------
// tail: atten2 + convs + final linear, all MFMA (16x16x32 bf16). (unchanged)
// ---------------------------------------------------------------------------
__global__ __launch_bounds__(256, 3) void tail_kernel(
    const float* __restrict__ eu, const float* __restrict__ ei, const float* __restrict__ et,
    const unsigned* __restrict__ aoB,
    const float* __restrict__ U, const float* __restrict__ q, const float* __restrict__ p,
    const float* __restrict__ Wbit, const float* __restrict__ Wv1,
    const float* __restrict__ Wv2, const float* __restrict__ Wv3,
    const float* __restrict__ Wf, const float* __restrict__ bfv,
    float* __restrict__ out)
{
    __shared__ __align__(16) unsigned short uitA[48 * 72];
    __shared__ __align__(16) unsigned short eNA[48 * 72];
    __shared__ __align__(16) unsigned short wcf[6 * 64 * 8];
    __shared__ __align__(16) unsigned short c_sh[16 * 584];
    __shared__ float G_sh[48 * 52];
    __shared__ float xpart[4 * 48];
    __shared__ float bcoef[16 * 4];

    const int t = threadIdx.x;
    const int lane = t & 63;
    const int wv = t >> 6;
    const int l15 = lane & 15;
    const int quad = lane >> 4;
    const int type = blockIdx.y;
    const float* xf = (type == 0) ? eu : (type == 1) ? ei : et;
    const int cw = wv * 16 + l15;
    const float qv = q[cw], pv = p[cw], bfb = bfv[cw];

    float wb[8][3];
    #pragma unroll
    for (int c = 0; c < 8; ++c)
        #pragma unroll
        for (int s = 0; s < 3; ++s) wb[c][s] = Wbit[c * 3 + s];

    bf16x8 ufrag[2];
    #pragma unroll
    for (int ks = 0; ks < 2; ++ks)
        #pragma unroll
        for (int j = 0; j < 8; ++j) {
            int f = ks * 32 + quad * 8 + j;
            ufrag[ks][j] = (short)f2bf(U[f * 64 + cw]);
        }
    bf16x8 wff[18];
    #pragma unroll
    for (int ks = 0; ks < 18; ++ks)
        #pragma unroll
        for (int j = 0; j < 8; ++j) {
            int k = ks * 32 + quad * 8 + j;
            float w = (k < 560) ? Wf[(size_t)k * 64 + cw] : 0.f;
            wff[ks][j] = (short)f2bf(w);
        }
    for (int slot = t; slot < 384; slot += 256) {
        int fi = slot >> 6, l = slot & 63;
        int nt_ = fi >> 1, ks = fi & 1;
        int r = nt_ * 16 + (l & 15);
        unsigned short vals[8];
        #pragma unroll
        for (int j = 0; j < 8; ++j) {
            int f = ks * 32 + (l >> 4) * 8 + j;
            float wv_;
            if (r < 8)       wv_ = Wv1[r * 64 + f];
            else if (r < 24) { int u = r - 8;  wv_ = Wv2[(u >> 1) * 128 + (u & 1) * 64 + f]; }
            else             { int u = r - 24; wv_ = Wv3[(u / 3) * 192 + (u % 3) * 64 + f]; }
            vals[j] = f2bf(wv_);
        }
        uint4 pk = { (unsigned)vals[0] | ((unsigned)vals[1] << 16),
                     (unsigned)vals[2] | ((unsigned)vals[3] << 16),
                     (unsigned)vals[4] | ((unsigned)vals[5] << 16),
                     (unsigned)vals[6] | ((unsigned)vals[7] << 16) };
        *(uint4*)&wcf[slot * 8] = pk;
    }

    for (int tile = blockIdx.x; tile < NT; tile += gridDim.x) {
        const int nodeBase = tile * 16;
        __syncthreads();
        #pragma unroll
        for (int i = 0; i < 3; ++i) {
            int idx = t + i * 256;
            int row = idx >> 4, cg = idx & 15;
            int nl = row / 3, s = row - nl * 3;
            int n = nodeBase + nl;
            uint2 pk;
            if (s == type) {
                float4 v4 = (n < NN) ? *(const float4*)(xf + (size_t)n * 64 + cg * 4)
                                     : make_float4(0.f, 0.f, 0.f, 0.f);
                pk.x = pack2(v4.x, v4.y); pk.y = pack2(v4.z, v4.w);
            } else {
                int aoidx = (type == 0) ? (s - 1)
                          : (type == 1) ? ((s == 0) ? 2 : 3)
                                        : ((s == 0) ? 4 : 5);
                pk = (n < NN) ? *(const uint2*)(aoB + ((size_t)aoidx * NN + n) * 32 + cg * 2)
                              : make_uint2(0u, 0u);
            }
            *(uint2*)&uitA[row * 72 + cg * 4] = pk;
        }
        __syncthreads();
        {
            f32x4 av[3];
            #pragma unroll
            for (int mt = 0; mt < 3; ++mt) { av[mt].x = 0; av[mt].y = 0; av[mt].z = 0; av[mt].w = 0; }
            #pragma unroll
            for (int mt = 0; mt < 3; ++mt)
                #pragma unroll
                for (int ks = 0; ks < 2; ++ks) {
                    bf16x8 a = *(const bf16x8*)&uitA[(mt * 16 + l15) * 72 + ks * 32 + quad * 8];
                    av[mt] = __builtin_amdgcn_mfma_f32_16x16x32_bf16(a, ufrag[ks], av[mt], 0, 0, 0);
                }
            #pragma unroll
            for (int mt = 0; mt < 3; ++mt)
                #pragma unroll
                for (int r = 0; r < 4; ++r) {
                    float val = fmaxf(av[mt][r] + qv, 0.f) * pv;
                    val += __shfl_xor(val, 1, 64); val += __shfl_xor(val, 2, 64);
                    val += __shfl_xor(val, 4, 64); val += __shfl_xor(val, 8, 64);
                    if (l15 == 0) xpart[wv * 48 + mt * 16 + quad * 4 + r] = val;
                }
        }
        __syncthreads();
        if (t < 16) {
            float xv[3];
            #pragma unroll
            for (int s = 0; s < 3; ++s)
                xv[s] = xpart[t * 3 + s] + xpart[48 + t * 3 + s]
                      + xpart[96 + t * 3 + s] + xpart[144 + t * 3 + s];
            float mm = fmaxf(xv[0], fmaxf(xv[1], xv[2]));
            float e0 = __expf(xv[0] - mm), e1 = __expf(xv[1] - mm), e2 = __expf(xv[2] - mm);
            float inv = 1.f / (e0 + e1 + e2);
            bcoef[t * 4 + 0] = e0 * inv; bcoef[t * 4 + 1] = e1 * inv; bcoef[t * 4 + 2] = e2 * inv;
        }
        __syncthreads();
        #pragma unroll
        for (int i = 0; i < 2; ++i) {
            int task = t + i * 256;
            int nl = task >> 5, fp = task & 31;
            float b0 = bcoef[nl * 4], b1 = bcoef[nl * 4 + 1], b2 = bcoef[nl * 4 + 2];
            unsigned u0 = *(const unsigned*)&uitA[(nl * 3 + 0) * 72 + fp * 2];
            unsigned u1 = *(const unsigned*)&uitA[(nl * 3 + 1) * 72 + fp * 2];
            unsigned u2 = *(const unsigned*)&uitA[(nl * 3 + 2) * 72 + fp * 2];
            float e0l = b0 * bflo(u0), e0h = b0 * bfhi(u0);
            float e1l = b1 * bflo(u1), e1h = b1 * bfhi(u1);
            float e2l = b2 * bflo(u2), e2h = b2 * bfhi(u2);
            *(unsigned*)&eNA[(nl * 3 + 0) * 72 + fp * 2] = pack2(e0l, e0h);
            *(unsigned*)&eNA[(nl * 3 + 1) * 72 + fp * 2] = pack2(e1l, e1h);
            *(unsigned*)&eNA[(nl * 3 + 2) * 72 + fp * 2] = pack2(e2l, e2h);
            #pragma unroll
            for (int c = 0; c < 8; ++c) {
                float lo = fmaxf(wb[c][0] * e0l + wb[c][1] * e1l + wb[c][2] * e2l, 0.f);
                float hi = fmaxf(wb[c][0] * e0h + wb[c][1] * e1h + wb[c][2] * e2h, 0.f);
                *(unsigned*)&c_sh[nl * 584 + c * 64 + fp * 2] = pack2(lo, hi);
            }
        }
        __syncthreads();
        #pragma unroll
        for (int pi = 0; pi < 3; ++pi) {
            int pr = wv + pi * 4;
            if (pr < 9) {
                int mm = pr / 3, nn_ = pr - mm * 3;
                f32x4 g; g.x = 0; g.y = 0; g.z = 0; g.w = 0;
                #pragma unroll
                for (int ks = 0; ks < 2; ++ks) {
                    bf16x8 a = *(const bf16x8*)&eNA[(mm * 16 + l15) * 72 + ks * 32 + quad * 8];
                    bf16x8 b = *(const bf16x8*)&wcf[((nn_ * 2 + ks) * 64 + lane) * 8];
                    g = __builtin_amdgcn_mfma_f32_16x16x32_bf16(a, b, g, 0, 0, 0);
                }
                #pragma unroll
                for (int r = 0; r < 4; ++r)
                    G_sh[(mm * 16 + quad * 4 + r) * 52 + nn_ * 16 + l15] = g[r];
            }
        }
        __syncthreads();
        #pragma unroll
        for (int i = 0; i < 4; ++i) {
            int task = t + i * 256;
            int vvv = task >> 4, nl = task & 15;
            unsigned short res = 0;
            if (vvv < 24) {
                int c = vvv / 3, s = vvv - c * 3;
                res = f2bf(fmaxf(G_sh[(nl * 3 + s) * 52 + c], 0.f));
            } else if (vvv < 40) {
                int u = vvv - 24, c = u >> 1, s = u & 1;
                float val = G_sh[(nl * 3 + s) * 52 + 8 + 2 * c]
                          + G_sh[(nl * 3 + s + 1) * 52 + 8 + 2 * c + 1];
                res = f2bf(fmaxf(val, 0.f));
            } else if (vvv < 48) {
                int c = vvv - 40;
                float val = G_sh[(nl * 3 + 0) * 52 + 24 + 3 * c]
                          + G_sh[(nl * 3 + 1) * 52 + 24 + 3 * c + 1]
                          + G_sh[(nl * 3 + 2) * 52 + 24 + 3 * c + 2];
                res = f2bf(fmaxf(val, 0.f));
            }
            c_sh[nl * 584 + 512 + vvv] = res;
        }
        __syncthreads();
        {
            f32x4 acc; acc.x = 0; acc.y = 0; acc.z = 0; acc.w = 0;
            const unsigned short* ap = &c_sh[l15 * 584 + quad * 8];
            #pragma unroll
            for (int ks = 0; ks < 18; ++ks) {
                bf16x8 a = *(const bf16x8*)(ap + ks * 32);
                acc = __builtin_amdgcn_mfma_f32_16x16x32_bf16(a, wff[ks], acc, 0, 0, 0);
            }
            float* outT = out + (size_t)type * NN * 64;
            #pragma unroll
            for (int r = 0; r < 4; ++r) {
                int node = nodeBase + quad * 4 + r;
                if (node < NN) outT[(size_t)node * 64 + cw] = fmaxf(acc[r] + bfb, 0.f);
            }
        }
    }
}

// ---------------------------------------------------------------------------
extern "C" void kernel_launch(void* const* d_in, const int* in_sizes, int n_in,
                              void* d_out, int out_size, void* d_ws, size_t ws_size,
                              hipStream_t stream)
{
    const float* eu = (const float*)d_in[0];
    const float* ei = (const float*)d_in[1];
    const float* et = (const float*)d_in[2];
    const float* ew = (const float*)d_in[3];
    const int* u_iw_j = (const int*)d_in[4];
    const int* u_iw_w = (const int*)d_in[5];
    const int* u_tw_j = (const int*)d_in[6];
    const int* u_tw_w = (const int*)d_in[7];
    const int* i_uw_j = (const int*)d_in[8];
    const int* i_uw_w = (const int*)d_in[9];
    const int* i_tw_j = (const int*)d_in[10];
    const int* i_tw_w = (const int*)d_in[11];
    const int* t_uw_j = (const int*)d_in[12];
    const int* t_uw_w = (const int*)d_in[13];
    const int* t_iw_j = (const int*)d_in[14];
    const int* t_iw_w = (const int*)d_in[15];
    const float* W1_user = (const float*)d_in[16];
    const float* W2_user = (const float*)d_in[17];
    const float* b_user  = (const float*)d_in[18];
    const float* v_user  = (const float*)d_in[19];
    const float* W1_item = (const float*)d_in[20];
    const float* W2_item = (const float*)d_in[21];
    const float* b_item  = (const float*)d_in[22];
    const float* v_item  = (const float*)d_in[23];
    const float* W1_tag  = (const float*)d_in[24];
    const float* W2_tag  = (const float*)d_in[25];
    const float* b_tag   = (const float*)d_in[26];
    const float* v_tag   = (const float*)d_in[27];
    const float* U    = (const float*)d_in[28];
    const float* q    = (const float*)d_in[29];
    const float* p    = (const float*)d_in[30];
    const float* Wbit = (const float*)d_in[31];
    const float* Wv1  = (const float*)d_in[32];
    const float* Wv2  = (const float*)d_in[33];
    const float* Wv3  = (const float*)d_in[34];
    const float* Wf   = (const float*)d_in[35];
    const float* bfv  = (const float*)d_in[36];
    float* out = (float*)d_out;

    // ---- workspace (110.4 MB):
    // gw8: 3*E*64 B = 57.6 MB | preB: 6*N*128 B = 19.2 MB
    // JG:  3*N*192 B = 14.4 MB | aoB: 6*N*128 B = 19.2 MB
    unsigned char* gw8 = (unsigned char*)d_ws;
    unsigned* preB = (unsigned*)(gw8 + (size_t)3 * EE * 64);
    unsigned char* JG = (unsigned char*)(preB + (size_t)6 * NN * 32);
    unsigned* aoB = (unsigned*)(JG + (size_t)3 * NN * 192);

    const dim3 blk(256);

    head_kernel<<<ET64 + 3 * NT64, blk, 0, stream>>>(
        ew, eu, ei, et,
        W1_user, W1_item, W1_tag, W2_user, W2_item, W2_tag,
        b_user, b_item, b_tag, gw8, preB, JG);

    atten1_kernel<<<dim3(NN / 4, 6), blk, 0, stream>>>(
        preB, gw8, JG, v_user, v_item, v_tag,
        u_iw_j, u_iw_w, u_tw_j, u_tw_w, i_uw_j, i_uw_w,
        i_tw_j, i_tw_w, t_uw_j, t_uw_w, t_iw_j, t_iw_w, aoB);

    tail_kernel<<<dim3(256, 3), blk, 0, stream>>>(
        eu, ei, et, aoB,
        U, q, p, Wbit, Wv1, Wv2, Wv3, Wf, bfv, out);
}

// Round 5
// 399.091 us; speedup vs baseline: 3.6768x; 1.1675x over previous
//
#include <hip/hip_runtime.h>
#include <math.h>

#define NN 25000
#define EE 300000
#define NT 1563          // ceil(25000/16)   (tail tiles)
#define NT64 391         // ceil(25000/64)   (ngemm tiles)
#define ET64 4688        // ceil(300000/64)  (egemm tiles)

typedef __attribute__((ext_vector_type(8))) short bf16x8;
typedef __attribute__((ext_vector_type(4))) float f32x4;
typedef __attribute__((ext_vector_type(2))) float f32x2;

__device__ __forceinline__ unsigned short f2bf(float f) {
    union { float f; unsigned u; } a; a.f = f;
    unsigned r = (a.u + 0x7fffu + ((a.u >> 16) & 1u)) >> 16;   // RNE
    return (unsigned short)r;
}
__device__ __forceinline__ unsigned pack2(float lo, float hi) {
    return (unsigned)f2bf(lo) | ((unsigned)f2bf(hi) << 16);
}
__device__ __forceinline__ float bflo(unsigned p) {
    union { unsigned u; float f; } a; a.u = p << 16; return a.f;
}
__device__ __forceinline__ float bfhi(unsigned p) {
    union { unsigned u; float f; } a; a.u = p & 0xffff0000u; return a.f;
}
// pack 4 floats -> 4 fp8(e4m3 OCP) in one uint
__device__ __forceinline__ unsigned packfp8x4(float a, float b, float c, float d) {
    int v = __builtin_amdgcn_cvt_pk_fp8_f32(a, b, 0, 0);
    v = __builtin_amdgcn_cvt_pk_fp8_f32(c, d, v, 1);
    return (unsigned)v;
}

// ---------------------------------------------------------------------------
// head: fused egemm + ngemm (one dispatch; block role from blockIdx.x).
//  egemm (blocks [0,ET64)): gw8[g][1+e] = fp8( ew[e] @ W1g[64:128,:] ); row 0 = 0
//  ngemm: per source X in {eu,ei,et}:
//    preB = bf16(X@Wa + ba), bf16(X@Wb + bb)
//    JG[y][1+n] = [ fp8(X@W2) 64B | bf16(X) 128B ] (192 B rows); row 0 = 0
// ---------------------------------------------------------------------------
__global__ __launch_bounds__(256) void head_kernel(
    const float* __restrict__ ew,
    const float* __restrict__ eu, const float* __restrict__ ei, const float* __restrict__ et,
    const float* __restrict__ W1u, const float* __restrict__ W1i, const float* __restrict__ W1t,
    const float* __restrict__ W2u, const float* __restrict__ W2i, const float* __restrict__ W2t,
    const float* __restrict__ bu, const float* __restrict__ bi, const float* __restrict__ bt,
    unsigned char* __restrict__ gw8, unsigned* __restrict__ preB,
    unsigned char* __restrict__ JG)
{
    __shared__ __align__(16) unsigned short stA[64 * 72];
    __shared__ __align__(16) float cS[64 * 68];
    const int t = threadIdx.x;
    const int lane = t & 63, wv = t >> 6;
    const int l15 = lane & 15, quad = lane >> 4;
    const int cw = wv * 16 + l15;                 // this wave's output col
    const int bx = blockIdx.x;

    if (bx < ET64) {
        // ================= egemm role =================
        if (bx == 0 && t < 48) {   // zero row 0 of the 3 gw8 tables (64 B each)
            int w = t >> 4;
            ((unsigned*)(gw8 + (size_t)w * (EE + 1) * 64))[t & 15] = 0u;
        }
        const float* Ws[3] = { W1u + 4096, W1i + 4096, W1t + 4096 };
        bf16x8 bf[3][2];
        #pragma unroll
        for (int w = 0; w < 3; ++w)
            #pragma unroll
            for (int ks = 0; ks < 2; ++ks)
                #pragma unroll
                for (int j = 0; j < 8; ++j)
                    bf[w][ks][j] = (short)f2bf(Ws[w][(ks * 32 + quad * 8 + j) * 64 + cw]);

        const int rowBase = bx * 64;
        #pragma unroll
        for (int i = 0; i < 4; ++i) {
            int idx = t + i * 256;
            int row = idx >> 4, cg = idx & 15;
            int gr = rowBase + row;
            float4 v4 = (gr < EE) ? *(const float4*)(ew + (size_t)gr * 64 + cg * 4)
                                  : make_float4(0.f, 0.f, 0.f, 0.f);
            uint2 pk = { pack2(v4.x, v4.y), pack2(v4.z, v4.w) };
            *(uint2*)&stA[row * 72 + cg * 4] = pk;
        }
        __syncthreads();
        bf16x8 af[4][2];
        #pragma unroll
        for (int m = 0; m < 4; ++m)
            #pragma unroll
            for (int ks = 0; ks < 2; ++ks)
                af[m][ks] = *(const bf16x8*)&stA[(m * 16 + l15) * 72 + ks * 32 + quad * 8];

        #pragma unroll
        for (int w = 0; w < 3; ++w) {
            if (w) __syncthreads();
            f32x4 acc[4];
            #pragma unroll
            for (int m = 0; m < 4; ++m) {
                acc[m].x = 0; acc[m].y = 0; acc[m].z = 0; acc[m].w = 0;
                #pragma unroll
                for (int ks = 0; ks < 2; ++ks)
                    acc[m] = __builtin_amdgcn_mfma_f32_16x16x32_bf16(af[m][ks], bf[w][ks], acc[m], 0, 0, 0);
                #pragma unroll
                for (int r = 0; r < 4; ++r)
                    cS[(m * 16 + quad * 4 + r) * 68 + cw] = acc[m][r];
            }
            __syncthreads();
            unsigned char* outg = gw8 + (size_t)w * (EE + 1) * 64 + 64;  // +1 row shift
            #pragma unroll
            for (int i = 0; i < 2; ++i) {
                int task = t + i * 256;               // 0..511
                int row = task >> 3, seg = task & 7;  // seg: 8 feats
                int gr = rowBase + row;
                if (gr < EE) {
                    float4 a = *(const float4*)&cS[row * 68 + seg * 8];
                    float4 b = *(const float4*)&cS[row * 68 + seg * 8 + 4];
                    uint2 pk = { packfp8x4(a.x, a.y, a.z, a.w),
                                 packfp8x4(b.x, b.y, b.z, b.w) };
                    *(uint2*)(outg + (size_t)gr * 64 + seg * 8) = pk;
                }
            }
        }
    } else {
        // ================= ngemm role =================
        const int yy = bx - ET64;
        const int y = yy / NT64;
        const int rowBase = (yy - y * NT64) * 64;
        if (rowBase == 0 && t < 48)   // zero row 0 of JG table y (192 B)
            ((unsigned*)(JG + (size_t)y * (NN + 1) * 192))[t] = 0u;
        const float* X; const float* Wa; const float* Wb; const float* W2;
        const float* ba; const float* bb; int oa, ob;
        switch (y) {
            case 0:  X = eu; Wa = W1i; ba = bi; oa = 0; Wb = W1t; bb = bt; ob = 1; W2 = W2u; break;
            case 1:  X = ei; Wa = W1u; ba = bu; oa = 2; Wb = W1t; bb = bt; ob = 3; W2 = W2i; break;
            default: X = et; Wa = W1u; ba = bu; oa = 4; Wb = W1i; bb = bi; ob = 5; W2 = W2t; break;
        }
        const float* Ws[3] = { Wa, Wb, W2 };
        const float bias_cw[3] = { ba[cw], bb[cw], 0.f };
        bf16x8 bf[3][2];
        #pragma unroll
        for (int w = 0; w < 3; ++w)
            #pragma unroll
            for (int ks = 0; ks < 2; ++ks)
                #pragma unroll
                for (int j = 0; j < 8; ++j)
                    bf[w][ks][j] = (short)f2bf(Ws[w][(ks * 32 + quad * 8 + j) * 64 + cw]);

        #pragma unroll
        for (int i = 0; i < 4; ++i) {
            int idx = t + i * 256;
            int row = idx >> 4, cg = idx & 15;
            int gr = rowBase + row;
            float4 v4 = (gr < NN) ? *(const float4*)(X + (size_t)gr * 64 + cg * 4)
                                  : make_float4(0.f, 0.f, 0.f, 0.f);
            uint2 pk = { pack2(v4.x, v4.y), pack2(v4.z, v4.w) };
            *(uint2*)&stA[row * 72 + cg * 4] = pk;
        }
        __syncthreads();
        bf16x8 af[4][2];
        #pragma unroll
        for (int m = 0; m < 4; ++m)
            #pragma unroll
            for (int ks = 0; ks < 2; ++ks)
                af[m][ks] = *(const bf16x8*)&stA[(m * 16 + l15) * 72 + ks * 32 + quad * 8];

        #pragma unroll
        for (int w = 0; w < 3; ++w) {
            if (w) __syncthreads();
            f32x4 acc[4];
            #pragma unroll
            for (int m = 0; m < 4; ++m) {
                acc[m].x = 0; acc[m].y = 0; acc[m].z = 0; acc[m].w = 0;
                #pragma unroll
                for (int ks = 0; ks < 2; ++ks)
                    acc[m] = __builtin_amdgcn_mfma_f32_16x16x32_bf16(af[m][ks], bf[w][ks], acc[m], 0, 0, 0);
                #pragma unroll
                for (int r = 0; r < 4; ++r)
                    cS[(m * 16 + quad * 4 + r) * 68 + cw] = acc[m][r] + bias_cw[w];
            }
            __syncthreads();
            #pragma unroll
            for (int i = 0; i < 2; ++i) {
                int task = t + i * 256;
                int row = task >> 3, seg = task & 7;
                int gr = rowBase + row;
                if (gr >= NN) continue;
                float4 a = *(const float4*)&cS[row * 68 + seg * 8];
                float4 b = *(const float4*)&cS[row * 68 + seg * 8 + 4];
                if (w < 2) {
                    int oi = (w == 0) ? oa : ob;
                    uint4 pk = { pack2(a.x, a.y), pack2(a.z, a.w),
                                 pack2(b.x, b.y), pack2(b.z, b.w) };
                    *(uint4*)(preB + ((size_t)oi * NN + gr) * 32 + seg * 4) = pk;
                } else {
                    unsigned char* dst = JG + ((size_t)y * (NN + 1) + gr + 1) * 192;
                    uint2 gj = { packfp8x4(a.x, a.y, a.z, a.w),
                                 packfp8x4(b.x, b.y, b.z, b.w) };
                    *(uint2*)(dst + seg * 8) = gj;
                    uint4 ej = *(const uint4*)&stA[row * 72 + seg * 8];
                    *(uint4*)(dst + 64 + seg * 16) = ej;
                }
            }
        }
    }
}

// ---------------------------------------------------------------------------
// atten1: all 6 aggregations in one dispatch (grid.y selects).
// New lane mapping: r=lane&15 owns features 4r..4r+3; q=lane>>4 owns k=4q..4q+3.
// Pre-shifted tables (index 0 = physical zero row) -> no branches.
// All gathers issued up front into register arrays (MLP).
// ---------------------------------------------------------------------------
__global__ __launch_bounds__(256) void atten1_kernel(
    const unsigned* __restrict__ preB, const unsigned char* __restrict__ gw8,
    const unsigned char* __restrict__ JG,
    const float* __restrict__ vu, const float* __restrict__ vi, const float* __restrict__ vt,
    const int* __restrict__ u_iw_j, const int* __restrict__ u_iw_w,
    const int* __restrict__ u_tw_j, const int* __restrict__ u_tw_w,
    const int* __restrict__ i_uw_j, const int* __restrict__ i_uw_w,
    const int* __restrict__ i_tw_j, const int* __restrict__ i_tw_w,
    const int* __restrict__ t_uw_j, const int* __restrict__ t_uw_w,
    const int* __restrict__ t_iw_j, const int* __restrict__ t_iw_w,
    unsigned* __restrict__ aoB)
{
    const int y = blockIdx.y;
    const int* Vj; const int* Vw; const float* v; int g;
    switch (y) {
        case 0:  Vj = u_iw_j; Vw = u_iw_w; v = vi; g = 1; break;
        case 1:  Vj = u_tw_j; Vw = u_tw_w; v = vt; g = 2; break;
        case 2:  Vj = i_uw_j; Vw = i_uw_w; v = vu; g = 0; break;
        case 3:  Vj = i_tw_j; Vw = i_tw_w; v = vt; g = 2; break;
        case 4:  Vj = t_uw_j; Vw = t_uw_w; v = vu; g = 0; break;
        default: Vj = t_iw_j; Vw = t_iw_w; v = vi; g = 1; break;
    }
    const unsigned* pre = preB + (size_t)y * NN * 32;
    const unsigned char* gw = gw8 + (size_t)g * (EE + 1) * 64;
    const unsigned char* jg = JG + (size_t)g * (NN + 1) * 192;
    unsigned*            out = aoB + (size_t)y * NN * 32;

    const int lane = threadIdx.x & 63;
    const int n = blockIdx.x * 4 + (threadIdx.x >> 6);
    const int q = lane >> 4, r = lane & 15;

    // per-lane node-static data: features 4r..4r+3
    const uint2 prep = *(const uint2*)(pre + (size_t)n * 32 + 2 * r);
    const float pf0 = bflo(prep.x), pf1 = bfhi(prep.x);
    const float pf2 = bflo(prep.y), pf3 = bfhi(prep.y);
    const float4 v4 = *(const float4*)(v + r * 4);

    // this lane's 4 neighbor slots: k = 4q..4q+3
    const int4 wi = *(const int4*)(Vw + n * 16 + q * 4);
    const int4 ji = *(const int4*)(Vj + n * 16 + q * 4);
    const int wid[4] = { wi.x, wi.y, wi.z, wi.w };
    const int jid[4] = { ji.x, ji.y, ji.z, ji.w };

    // issue ALL gathers first (12 independent loads in flight)
    unsigned gwv[4], gjv[4]; uint2 ejv[4];
    #pragma unroll
    for (int i = 0; i < 4; ++i)
        gwv[i] = *(const unsigned*)(gw + (size_t)wid[i] * 64 + r * 4);
    #pragma unroll
    for (int i = 0; i < 4; ++i) {
        const unsigned char* row = jg + (size_t)jid[i] * 192;
        gjv[i] = *(const unsigned*)(row + r * 4);
        ejv[i] = *(const uint2*)(row + 64 + r * 8);
    }

    // logits: x[k=4q+i] = sum_f relu(pre+gw+gj)*v, reduced over 16 r-lanes
    float xk[4];
    #pragma unroll
    for (int i = 0; i < 4; ++i) {
        f32x2 g01 = __builtin_amdgcn_cvt_pk_f32_fp8((int)gwv[i], false);
        f32x2 g23 = __builtin_amdgcn_cvt_pk_f32_fp8((int)gwv[i], true);
        f32x2 j01 = __builtin_amdgcn_cvt_pk_f32_fp8((int)gjv[i], false);
        f32x2 j23 = __builtin_amdgcn_cvt_pk_f32_fp8((int)gjv[i], true);
        float x =          fmaxf(pf0 + g01.x + j01.x, 0.f) * v4.x;
        x = fmaf(fmaxf(pf1 + g01.y + j01.y, 0.f), v4.y, x);
        x = fmaf(fmaxf(pf2 + g23.x + j23.x, 0.f), v4.z, x);
        x = fmaf(fmaxf(pf3 + g23.y + j23.y, 0.f), v4.w, x);
        x += __shfl_xor(x, 1, 64);
        x += __shfl_xor(x, 2, 64);
        x += __shfl_xor(x, 4, 64);
        x += __shfl_xor(x, 8, 64);
        xk[i] = x;
    }
    // softmax over 16 k (4 local regs x 4 q-groups)
    float m = fmaxf(fmaxf(xk[0], xk[1]), fmaxf(xk[2], xk[3]));
    m = fmaxf(m, __shfl_xor(m, 16, 64));
    m = fmaxf(m, __shfl_xor(m, 32, 64));
    float e0 = __expf(xk[0] - m), e1 = __expf(xk[1] - m);
    float e2 = __expf(xk[2] - m), e3 = __expf(xk[3] - m);
    float s = (e0 + e1) + (e2 + e3);
    s += __shfl_xor(s, 16, 64);
    s += __shfl_xor(s, 32, 64);
    const float inv = 1.f / s;

    // weighted ej sum: weights for this lane's k's are LOCAL
    float a0 = 0.f, a1 = 0.f, a2 = 0.f, a3 = 0.f;
    const float wgt[4] = { e0 * inv, e1 * inv, e2 * inv, e3 * inv };
    #pragma unroll
    for (int i = 0; i < 4; ++i) {
        a0 = fmaf(wgt[i], bflo(ejv[i].x), a0);
        a1 = fmaf(wgt[i], bfhi(ejv[i].x), a1);
        a2 = fmaf(wgt[i], bflo(ejv[i].y), a2);
        a3 = fmaf(wgt[i], bfhi(ejv[i].y), a3);
    }
    a0 += __shfl_xor(a0, 16, 64); a0 += __shfl_xor(a0, 32, 64);
    a1 += __shfl_xor(a1, 16, 64); a1 += __shfl_xor(a1, 32, 64);
    a2 += __shfl_xor(a2, 16, 64); a2 += __shfl_xor(a2, 32, 64);
    a3 += __shfl_xor(a3, 16, 64); a3 += __shfl_xor(a3, 32, 64);
    if (q == 0) {
        uint2 pk = { pack2(a0, a1), pack2(a2, a3) };
        *(uint2*)(out + (size_t)n * 32 + 2 * r) = pk;
    }
}

// ---------------------------------------------------------------------------
// tail: atten2 + convs + final linear, all MFMA (16x16x32 bf16). (unchanged)
// ---------------------------------------------------------------------------
__global__ __launch_bounds__(256, 3) void tail_kernel(
    const float* __restrict__ eu, const float* __restrict__ ei, const float* __restrict__ et,
    const unsigned* __restrict__ aoB,
    const float* __restrict__ U, const float* __restrict__ q, const float* __restrict__ p,
    const float* __restrict__ Wbit, const float* __restrict__ Wv1,
    const float* __restrict__ Wv2, const float* __restrict__ Wv3,
    const float* __restrict__ Wf, const float* __restrict__ bfv,
    float* __restrict__ out)
{
    __shared__ __align__(16) unsigned short uitA[48 * 72];
    __shared__ __align__(16) unsigned short eNA[48 * 72];
    __shared__ __align__(16) unsigned short wcf[6 * 64 * 8];
    __shared__ __align__(16) unsigned short c_sh[16 * 584];
    __shared__ float G_sh[48 * 52];
    __shared__ float xpart[4 * 48];
    __shared__ float bcoef[16 * 4];

    const int t = threadIdx.x;
    const int lane = t & 63;
    const int wv = t >> 6;
    const int l15 = lane & 15;
    const int quad = lane >> 4;
    const int type = blockIdx.y;
    const float* xf = (type == 0) ? eu : (type == 1) ? ei : et;
    const int cw = wv * 16 + l15;
    const float qv = q[cw], pv = p[cw], bfb = bfv[cw];

    float wb[8][3];
    #pragma unroll
    for (int c = 0; c < 8; ++c)
        #pragma unroll
        for (int s = 0; s < 3; ++s) wb[c][s] = Wbit[c * 3 + s];

    bf16x8 ufrag[2];
    #pragma unroll
    for (int ks = 0; ks < 2; ++ks)
        #pragma unroll
        for (int j = 0; j < 8; ++j) {
            int f = ks * 32 + quad * 8 + j;
            ufrag[ks][j] = (short)f2bf(U[f * 64 + cw]);
        }
    bf16x8 wff[18];
    #pragma unroll
    for (int ks = 0; ks < 18; ++ks)
        #pragma unroll
        for (int j = 0; j < 8; ++j) {
            int k = ks * 32 + quad * 8 + j;
            float w = (k < 560) ? Wf[(size_t)k * 64 + cw] : 0.f;
            wff[ks][j] = (short)f2bf(w);
        }
    for (int slot = t; slot < 384; slot += 256) {
        int fi = slot >> 6, l = slot & 63;
        int nt_ = fi >> 1, ks = fi & 1;
        int r = nt_ * 16 + (l & 15);
        unsigned short vals[8];
        #pragma unroll
        for (int j = 0; j < 8; ++j) {
            int f = ks * 32 + (l >> 4) * 8 + j;
            float wv_;
            if (r < 8)       wv_ = Wv1[r * 64 + f];
            else if (r < 24) { int u = r - 8;  wv_ = Wv2[(u >> 1) * 128 + (u & 1) * 64 + f]; }
            else             { int u = r - 24; wv_ = Wv3[(u / 3) * 192 + (u % 3) * 64 + f]; }
            vals[j] = f2bf(wv_);
        }
        uint4 pk = { (unsigned)vals[0] | ((unsigned)vals[1] << 16),
                     (unsigned)vals[2] | ((unsigned)vals[3] << 16),
                     (unsigned)vals[4] | ((unsigned)vals[5] << 16),
                     (unsigned)vals[6] | ((unsigned)vals[7] << 16) };
        *(uint4*)&wcf[slot * 8] = pk;
    }

    for (int tile = blockIdx.x; tile < NT; tile += gridDim.x) {
        const int nodeBase = tile * 16;
        __syncthreads();
        #pragma unroll
        for (int i = 0; i < 3; ++i) {
            int idx = t + i * 256;
            int row = idx >> 4, cg = idx & 15;
            int nl = row / 3, s = row - nl * 3;
            int n = nodeBase + nl;
            uint2 pk;
            if (s == type) {
                float4 v4 = (n < NN) ? *(const float4*)(xf + (size_t)n * 64 + cg * 4)
                                     : make_float4(0.f, 0.f, 0.f, 0.f);
                pk.x = pack2(v4.x, v4.y); pk.y = pack2(v4.z, v4.w);
            } else {
                int aoidx = (type == 0) ? (s - 1)
                          : (type == 1) ? ((s == 0) ? 2 : 3)
                                        : ((s == 0) ? 4 : 5);
                pk = (n < NN) ? *(const uint2*)(aoB + ((size_t)aoidx * NN + n) * 32 + cg * 2)
                              : make_uint2(0u, 0u);
            }
            *(uint2*)&uitA[row * 72 + cg * 4] = pk;
        }
        __syncthreads();
        {
            f32x4 av[3];
            #pragma unroll
            for (int mt = 0; mt < 3; ++mt) { av[mt].x = 0; av[mt].y = 0; av[mt].z = 0; av[mt].w = 0; }
            #pragma unroll
            for (int mt = 0; mt < 3; ++mt)
                #pragma unroll
                for (int ks = 0; ks < 2; ++ks) {
                    bf16x8 a = *(const bf16x8*)&uitA[(mt * 16 + l15) * 72 + ks * 32 + quad * 8];
                    av[mt] = __builtin_amdgcn_mfma_f32_16x16x32_bf16(a, ufrag[ks], av[mt], 0, 0, 0);
                }
            #pragma unroll
            for (int mt = 0; mt < 3; ++mt)
                #pragma unroll
                for (int r = 0; r < 4; ++r) {
                    float val = fmaxf(av[mt][r] + qv, 0.f) * pv;
                    val += __shfl_xor(val, 1, 64); val += __shfl_xor(val, 2, 64);
                    val += __shfl_xor(val, 4, 64); val += __shfl_xor(val, 8, 64);
                    if (l15 == 0) xpart[wv * 48 + mt * 16 + quad * 4 + r] = val;
                }
        }
        __syncthreads();
        if (t < 16) {
            float xv[3];
            #pragma unroll
            for (int s = 0; s < 3; ++s)
                xv[s] = xpart[t * 3 + s] + xpart[48 + t * 3 + s]
                      + xpart[96 + t * 3 + s] + xpart[144 + t * 3 + s];
            float mm = fmaxf(xv[0], fmaxf(xv[1], xv[2]));
            float e0 = __expf(xv[0] - mm), e1 = __expf(xv[1] - mm), e2 = __expf(xv[2] - mm);
            float inv = 1.f / (e0 + e1 + e2);
            bcoef[t * 4 + 0] = e0 * inv; bcoef[t * 4 + 1] = e1 * inv; bcoef[t * 4 + 2] = e2 * inv;
        }
        __syncthreads();
        #pragma unroll
        for (int i = 0; i < 2; ++i) {
            int task = t + i * 256;
            int nl = task >> 5, fp = task & 31;
            float b0 = bcoef[nl * 4], b1 = bcoef[nl * 4 + 1], b2 = bcoef[nl * 4 + 2];
            unsigned u0 = *(const unsigned*)&uitA[(nl * 3 + 0) * 72 + fp * 2];
            unsigned u1 = *(const unsigned*)&uitA[(nl * 3 + 1) * 72 + fp * 2];
            unsigned u2 = *(const unsigned*)&uitA[(nl * 3 + 2) * 72 + fp * 2];
            float e0l = b0 * bflo(u0), e0h = b0 * bfhi(u0);
            float e1l = b1 * bflo(u1), e1h = b1 * bfhi(u1);
            float e2l = b2 * bflo(u2), e2h = b2 * bfhi(u2);
            *(unsigned*)&eNA[(nl * 3 + 0) * 72 + fp * 2] = pack2(e0l, e0h);
            *(unsigned*)&eNA[(nl * 3 + 1) * 72 + fp * 2] = pack2(e1l, e1h);
            *(unsigned*)&eNA[(nl * 3 + 2) * 72 + fp * 2] = pack2(e2l, e2h);
            #pragma unroll
            for (int c = 0; c < 8; ++c) {
                float lo = fmaxf(wb[c][0] * e0l + wb[c][1] * e1l + wb[c][2] * e2l, 0.f);
                float hi = fmaxf(wb[c][0] * e0h + wb[c][1] * e1h + wb[c][2] * e2h, 0.f);
                *(unsigned*)&c_sh[nl * 584 + c * 64 + fp * 2] = pack2(lo, hi);
            }
        }
        __syncthreads();
        #pragma unroll
        for (int pi = 0; pi < 3; ++pi) {
            int pr = wv + pi * 4;
            if (pr < 9) {
                int mm = pr / 3, nn_ = pr - mm * 3;
                f32x4 g; g.x = 0; g.y = 0; g.z = 0; g.w = 0;
                #pragma unroll
                for (int ks = 0; ks < 2; ++ks) {
                    bf16x8 a = *(const bf16x8*)&eNA[(mm * 16 + l15) * 72 + ks * 32 + quad * 8];
                    bf16x8 b = *(const bf16x8*)&wcf[((nn_ * 2 + ks) * 64 + lane) * 8];
                    g = __builtin_amdgcn_mfma_f32_16x16x32_bf16(a, b, g, 0, 0, 0);
                }
                #pragma unroll
                for (int r = 0; r < 4; ++r)
                    G_sh[(mm * 16 + quad * 4 + r) * 52 + nn_ * 16 + l15] = g[r];
            }
        }
        __syncthreads();
        #pragma unroll
        for (int i = 0; i < 4; ++i) {
            int task = t + i * 256;
            int vvv = task >> 4, nl = task & 15;
            unsigned short res = 0;
            if (vvv < 24) {
                int c = vvv / 3, s = vvv - c * 3;
                res = f2bf(fmaxf(G_sh[(nl * 3 + s) * 52 + c], 0.f));
            } else if (vvv < 40) {
                int u = vvv - 24, c = u >> 1, s = u & 1;
                float val = G_sh[(nl * 3 + s) * 52 + 8 + 2 * c]
                          + G_sh[(nl * 3 + s + 1) * 52 + 8 + 2 * c + 1];
                res = f2bf(fmaxf(val, 0.f));
            } else if (vvv < 48) {
                int c = vvv - 40;
                float val = G_sh[(nl * 3 + 0) * 52 + 24 + 3 * c]
                          + G_sh[(nl * 3 + 1) * 52 + 24 + 3 * c + 1]
                          + G_sh[(nl * 3 + 2) * 52 + 24 + 3 * c + 2];
                res = f2bf(fmaxf(val, 0.f));
            }
            c_sh[nl * 584 + 512 + vvv] = res;
        }
        __syncthreads();
        {
            f32x4 acc; acc.x = 0; acc.y = 0; acc.z = 0; acc.w = 0;
            const unsigned short* ap = &c_sh[l15 * 584 + quad * 8];
            #pragma unroll
            for (int ks = 0; ks < 18; ++ks) {
                bf16x8 a = *(const bf16x8*)(ap + ks * 32);
                acc = __builtin_amdgcn_mfma_f32_16x16x32_bf16(a, wff[ks], acc, 0, 0, 0);
            }
            float* outT = out + (size_t)type * NN * 64;
            #pragma unroll
            for (int r = 0; r < 4; ++r) {
                int node = nodeBase + quad * 4 + r;
                if (node < NN) outT[(size_t)node * 64 + cw] = fmaxf(acc[r] + bfb, 0.f);
            }
        }
    }
}

// ---------------------------------------------------------------------------
extern "C" void kernel_launch(void* const* d_in, const int* in_sizes, int n_in,
                              void* d_out, int out_size, void* d_ws, size_t ws_size,
                              hipStream_t stream)
{
    const float* eu = (const float*)d_in[0];
    const float* ei = (const float*)d_in[1];
    const float* et = (const float*)d_in[2];
    const float* ew = (const float*)d_in[3];
    const int* u_iw_j = (const int*)d_in[4];
    const int* u_iw_w = (const int*)d_in[5];
    const int* u_tw_j = (const int*)d_in[6];
    const int* u_tw_w = (const int*)d_in[7];
    const int* i_uw_j = (const int*)d_in[8];
    const int* i_uw_w = (const int*)d_in[9];
    const int* i_tw_j = (const int*)d_in[10];
    const int* i_tw_w = (const int*)d_in[11];
    const int* t_uw_j = (const int*)d_in[12];
    const int* t_uw_w = (const int*)d_in[13];
    const int* t_iw_j = (const int*)d_in[14];
    const int* t_iw_w = (const int*)d_in[15];
    const float* W1_user = (const float*)d_in[16];
    const float* W2_user = (const float*)d_in[17];
    const float* b_user  = (const float*)d_in[18];
    const float* v_user  = (const float*)d_in[19];
    const float* W1_item = (const float*)d_in[20];
    const float* W2_item = (const float*)d_in[21];
    const float* b_item  = (const float*)d_in[22];
    const float* v_item  = (const float*)d_in[23];
    const float* W1_tag  = (const float*)d_in[24];
    const float* W2_tag  = (const float*)d_in[25];
    const float* b_tag   = (const float*)d_in[26];
    const float* v_tag   = (const float*)d_in[27];
    const float* U    = (const float*)d_in[28];
    const float* q    = (const float*)d_in[29];
    const float* p    = (const float*)d_in[30];
    const float* Wbit = (const float*)d_in[31];
    const float* Wv1  = (const float*)d_in[32];
    const float* Wv2  = (const float*)d_in[33];
    const float* Wv3  = (const float*)d_in[34];
    const float* Wf   = (const float*)d_in[35];
    const float* bfv  = (const float*)d_in[36];
    float* out = (float*)d_out;

    // ---- workspace (~110 MB):
    // gw8: 3*(E+1)*64 B | preB: 6*N*128 B | JG: 3*(N+1)*192 B | aoB: 6*N*128 B
    unsigned char* gw8 = (unsigned char*)d_ws;
    unsigned* preB = (unsigned*)(gw8 + (size_t)3 * (EE + 1) * 64);
    unsigned char* JG = (unsigned char*)(preB + (size_t)6 * NN * 32);
    unsigned* aoB = (unsigned*)(JG + (size_t)3 * (NN + 1) * 192);

    const dim3 blk(256);

    head_kernel<<<ET64 + 3 * NT64, blk, 0, stream>>>(
        ew, eu, ei, et,
        W1_user, W1_item, W1_tag, W2_user, W2_item, W2_tag,
        b_user, b_item, b_tag, gw8, preB, JG);

    atten1_kernel<<<dim3(NN / 4, 6), blk, 0, stream>>>(
        preB, gw8, JG, v_user, v_item, v_tag,
        u_iw_j, u_iw_w, u_tw_j, u_tw_w, i_uw_j, i_uw_w,
        i_tw_j, i_tw_w, t_uw_j, t_uw_w, t_iw_j, t_iw_w, aoB);

    tail_kernel<<<dim3(256, 3), blk, 0, stream>>>(
        eu, ei, et, aoB,
        U, q, p, Wbit, Wv1, Wv2, Wv3, Wf, bfv, out);
}